// Round 15
// baseline (368.512 us; speedup 1.0000x reference)
//
#include <hip/hip_runtime.h>
#include <math.h>

#define D_MODEL 1024
#define D_INNER 2048
#define DPROJ   96      // DT_RANK + 2*D_STATE
#define DT_RANK 64
#define NSTATE  16
#define SEQ     2048
#define CL      16      // chunk length for scan
#define NCH     (SEQ/CL)            // 128
#define SCAN_SEGS 4
#define SCAN_CPS  (NCH / SCAN_SEGS) // 32 chunks per segment-lane
#define LOG2E   1.44269504088896340736f
#define TDC     ((size_t)SEQ * D_MODEL)   // compile-time TD stride for partials
#define XZP1    ((size_t)SEQ * 4096)      // offset of in_proj partial 1 (ushorts)

typedef unsigned short ushort_t;
typedef short v8s __attribute__((ext_vector_type(8)));
typedef unsigned short u8s __attribute__((ext_vector_type(8)));
typedef float v4f __attribute__((ext_vector_type(4)));
typedef __attribute__((address_space(3))) unsigned int as3_u32;
typedef __attribute__((address_space(1))) unsigned int as1_u32;

__device__ __forceinline__ float silu_f(float x) { return x / (1.f + expf(-x)); }

__device__ __forceinline__ ushort_t f2bf(float f) {
  union { float f; unsigned u; } x; x.f = f;
  unsigned r = x.u + 0x7fffu + ((x.u >> 16) & 1u);  // RNE; inputs finite
  return (ushort_t)(r >> 16);
}
__device__ __forceinline__ float bf2f(ushort_t b) {
  union { unsigned u; float f; } x; x.u = ((unsigned)b) << 16; return x.f;
}

// async global->LDS, 16B per lane; lds dest = wave-uniform base + lane*16
__device__ __forceinline__ void gl_lds16(const ushort_t* g, ushort_t* l) {
  __builtin_amdgcn_global_load_lds((const as1_u32*)g, (as3_u32*)l, 16, 0, 0);
}

// x = (pN ? sum of nparts bf16 partials : a) (+ b); res_out = x;
// xn = rmsnorm(x)*w -> f32 (xnf) and/or bf16 (xnb)
__global__ __launch_bounds__(256) void addrms_kernel(
    const float* __restrict__ a, const ushort_t* __restrict__ pN, int nparts,
    const float* __restrict__ b,
    const float* __restrict__ w, float* __restrict__ res_out,
    float* __restrict__ xnf, ushort_t* __restrict__ xnb) {
  int t = blockIdx.x;
  int tid = threadIdx.x;
  float v[4];
  float ss = 0.f;
#pragma unroll
  for (int j = 0; j < 4; ++j) {
    int dcol = tid + j * 256;
    size_t off = (size_t)t * D_MODEL + dcol;
    float x;
    if (pN) {
      x = 0.f;
      for (int p = 0; p < nparts; ++p) x += bf2f(pN[off + (size_t)p * TDC]);
    } else {
      x = a[off];
    }
    if (b) x += b[off];
    v[j] = x;
    ss += x * x;
  }
#pragma unroll
  for (int off = 32; off > 0; off >>= 1) ss += __shfl_down(ss, off);
  __shared__ float red[4];
  __shared__ float rmsv;
  int wid = tid >> 6, lane = tid & 63;
  if (lane == 0) red[wid] = ss;
  __syncthreads();
  if (tid == 0) {
    float s = red[0] + red[1] + red[2] + red[3];
    rmsv = rsqrtf(s / (float)D_MODEL + 1e-5f);
  }
  __syncthreads();
  float r = rmsv;
#pragma unroll
  for (int j = 0; j < 4; ++j) {
    int dcol = tid + j * 256;
    if (res_out) res_out[(size_t)t * D_MODEL + dcol] = v[j];
    float xn = v[j] * r * w[dcol];
    if (xnf) xnf[(size_t)t * D_MODEL + dcol] = xn;
    if (xnb) xnb[(size_t)t * D_MODEL + dcol] = f2bf(xn);
  }
}

// single-dispatch f32->bf16 of all 4 weight tensors (both layers each)
__global__ __launch_bounds__(256) void f2bf_all_kernel(
    const float* __restrict__ s0, ushort_t* __restrict__ d0, int n0,
    const float* __restrict__ s1, ushort_t* __restrict__ d1, int n1,
    const float* __restrict__ s2, ushort_t* __restrict__ d2, int n2,
    const float* __restrict__ s3, ushort_t* __restrict__ d3, int n3) {
  int j = blockIdx.x * 256 + threadIdx.x;
  const float* s; ushort_t* d;
  if (j < n0) { s = s0; d = d0; }
  else {
    j -= n0;
    if (j < n1) { s = s1; d = d1; }
    else {
      j -= n1;
      if (j < n2) { s = s2; d = d2; }
      else {
        j -= n2;
        if (j >= n3) return;
        s = s3; d = d3;
      }
    }
  }
  float4 v = ((const float4*)s)[j];
  ushort4 o;
  o.x = f2bf(v.x); o.y = f2bf(v.y); o.z = f2bf(v.z); o.w = f2bf(v.w);
  ((ushort4*)d)[j] = o;
}

// ------------- bf16 MFMA GEMM (NT): C[m,n] = sum_k A[m,k]*B[n,k] -------------
// m97 structure + double-buffered prefetch; one __syncthreads per K-step.
// XCD-aware bijective block swizzle (m204). SPLITK>1: partials at z*M*ldc.
// EPI: 0 = f32 out, 1 = softplus(acc+bias[col]) -> bf16, 2 = bf16.
template <int SPLITK, bool CLAMPN, int EPI>
__global__ __launch_bounds__(256) void gemm_bt(
    const ushort_t* __restrict__ A, const ushort_t* __restrict__ B,
    void* __restrict__ Cv, const float* __restrict__ bias,
    int M, int N, int K, int lda, int ldb, int ldc) {
  __shared__ ushort_t As[2][128 * 32];
  __shared__ ushort_t Bs[2][128 * 32];
  int tid = threadIdx.x;

  // bijective XCD swizzle of the flattened block id
  int gx = gridDim.x, gy = gridDim.y;
  int nwg = gx * gy * gridDim.z;
  int phys = blockIdx.x + gx * (blockIdx.y + gy * blockIdx.z);
  int q = nwg >> 3, r = nwg & 7;
  int xcd = phys & 7, idx8 = phys >> 3;
  int lbid = (xcd < r ? xcd * (q + 1) : r * (q + 1) + (xcd - r) * q) + idx8;
  int bx = lbid % gx, by = (lbid / gx) % gy, bz = lbid / (gx * gy);

  int bm = by * 128;
  int bn = bx * 128;
  int kchunk = K / SPLITK;
  int k0 = bz * kchunk;
  int nk = kchunk / 32;

  int lane = tid & 63, wid = tid >> 6;
  int wr = wid >> 1, wc = wid & 1;
  int lr = lane & 15;
  int ko = (lane >> 4) * 8;

  int rs0 = wid * 16 + (lane >> 2);
  int segc = (lane & 3) * 8;

  auto stage = [&](int buf, int kt) {
#pragma unroll
    for (int s = 0; s < 2; ++s) {
      int r2 = s * 64 + rs0;
      int cc = kt + segc;
      gl_lds16(A + (size_t)(bm + r2) * lda + cc, &As[buf][s * 2048 + wid * 512]);
      int bc = bn + r2;
      if (CLAMPN) bc = min(bc, N - 1);   // in-bounds; junk cols never stored
      gl_lds16(B + (size_t)bc * ldb + cc, &Bs[buf][s * 2048 + wid * 512]);
    }
  };

  v4f acc[4][4] = {};

  stage(0, k0);
  __syncthreads();
  int cur = 0;
  for (int it = 0; it < nk; ++it) {
    if (it + 1 < nk) stage(cur ^ 1, k0 + (it + 1) * 32);
    v8s a[4], b[4];
#pragma unroll
    for (int m = 0; m < 4; ++m)
      a[m] = *(const v8s*)&As[cur][(wr * 64 + m * 16 + lr) * 32 + ko];
#pragma unroll
    for (int n = 0; n < 4; ++n)
      b[n] = *(const v8s*)&Bs[cur][(wc * 64 + n * 16 + lr) * 32 + ko];
#pragma unroll
    for (int m = 0; m < 4; ++m)
#pragma unroll
      for (int n = 0; n < 4; ++n)
        acc[m][n] = __builtin_amdgcn_mfma_f32_16x16x32_bf16(a[m], b[n], acc[m][n], 0, 0, 0);
    __syncthreads();
    cur ^= 1;
  }

  float* Cf = (float*)Cv;
  ushort_t* Cb = (ushort_t*)Cv;
  size_t zoff = (SPLITK > 1) ? (size_t)bz * (size_t)M * (size_t)ldc : 0;

#pragma unroll
  for (int m = 0; m < 4; ++m) {
#pragma unroll
    for (int n = 0; n < 4; ++n) {
      int gc = bn + wc * 64 + n * 16 + lr;
      if (gc >= N) continue;
      int gr0 = bm + wr * 64 + m * 16 + (lane >> 4) * 4;
      float bv = (EPI == 1) ? bias[gc] : 0.f;
#pragma unroll
      for (int j = 0; j < 4; ++j) {
        float val = acc[m][n][j];
        size_t idx = zoff + (size_t)(gr0 + j) * ldc + gc;
        if (EPI == 0) {
          Cf[idx] = val;
        } else if (EPI == 1) {
          float x = val + bv;
          x = fmaxf(x, 0.f) + log1pf(expf(-fabsf(x)));
          Cb[idx] = f2bf(x);
        } else {
          Cb[idx] = f2bf(val);
        }
      }
    }
  }
}

// ---------- fused conv_silu + x_proj K-slice GEMM ----------
// xz input arrives as TWO bf16 split-K partials (summed at load).
__global__ __launch_bounds__(256) void convxproj_kernel(
    const ushort_t* __restrict__ xzp, const float* __restrict__ cw,
    const float* __restrict__ cb, const ushort_t* __restrict__ Bw,
    ushort_t* __restrict__ xcb, ushort_t* __restrict__ pkb) {
  __shared__ ushort_t As[128][136];   // 272B rows: 16B-aligned, 2-way banks
  __shared__ ushort_t Bs[2][128 * 32];
  int tid = threadIdx.x;
  int bm = blockIdx.y * 128;
  int c0s = blockIdx.z * 128;         // channel / K-slice offset
  int k0 = c0s;

  // ---- phase 1: conv ----
  {
    int quad = tid & 31;              // 4 channels each
    int tg = tid >> 5;                // 8 groups x 16 t
    int cc = c0s + quad * 4;
    int tbase = bm + tg * 16;
    float4 cbv = *(const float4*)&cb[cc];
    float4 wv[4];
#pragma unroll
    for (int i = 0; i < 4; ++i) wv[i] = *(const float4*)&cw[(cc + i) * 4];
    float rw[4][4];                   // ring of last 4 rows (compile-time idx)
#pragma unroll
    for (int p = 0; p < 3; ++p) {
      int ts = tbase - 3 + p;
      if (ts < 0) {
        rw[p][0] = rw[p][1] = rw[p][2] = rw[p][3] = 0.f;
      } else {
        ushort4 x0 = *(const ushort4*)&xzp[(size_t)ts * 4096 + cc];
        ushort4 x1 = *(const ushort4*)&xzp[XZP1 + (size_t)ts * 4096 + cc];
        rw[p][0] = bf2f(x0.x) + bf2f(x1.x);
        rw[p][1] = bf2f(x0.y) + bf2f(x1.y);
        rw[p][2] = bf2f(x0.z) + bf2f(x1.z);
        rw[p][3] = bf2f(x0.w) + bf2f(x1.w);
      }
    }
#pragma unroll
    for (int j = 0; j < 16; ++j) {
      int t = tbase + j;
      {
        ushort4 x0 = *(const ushort4*)&xzp[(size_t)t * 4096 + cc];
        ushort4 x1 = *(const ushort4*)&xzp[XZP1 + (size_t)t * 4096 + cc];
        rw[(3 + j) & 3][0] = bf2f(x0.x) + bf2f(x1.x);
        rw[(3 + j) & 3][1] = bf2f(x0.y) + bf2f(x1.y);
        rw[(3 + j) & 3][2] = bf2f(x0.z) + bf2f(x1.z);
        rw[(3 + j) & 3][3] = bf2f(x0.w) + bf2f(x1.w);
      }
      float acc[4] = {cbv.x, cbv.y, cbv.z, cbv.w};
#pragma unroll
      for (int k = 0; k < 4; ++k) {
#pragma unroll
        for (int i = 0; i < 4; ++i)
          acc[i] = fmaf(rw[(j + k) & 3][i], ((const float*)&wv[i])[k], acc[i]);
      }
      ushort4 o;
      o.x = f2bf(silu_f(acc[0]));
      o.y = f2bf(silu_f(acc[1]));
      o.z = f2bf(silu_f(acc[2]));
      o.w = f2bf(silu_f(acc[3]));
      *(ushort4*)&As[tg * 16 + j][quad * 4] = o;
      *(ushort4*)&xcb[(size_t)t * D_INNER + cc] = o;
    }
  }

  // ---- phase 2: GEMM (A resident in LDS) ----
  int lane = tid & 63, wid = tid >> 6;
  int wr = wid >> 1, wc = wid & 1;
  int lr = lane & 15;
  int ko = (lane >> 4) * 8;
  int rs0 = wid * 16 + (lane >> 2);
  int segc = (lane & 3) * 8;

  auto stageB = [&](int buf, int it) {
#pragma unroll
    for (int s = 0; s < 2; ++s) {
      int r2 = s * 64 + rs0;
      int bc = min(r2, DPROJ - 1);
      int cc2 = k0 + it * 32 + segc;
      gl_lds16(Bw + (size_t)bc * D_INNER + cc2, &Bs[buf][s * 2048 + wid * 512]);
    }
  };

  v4f acc[4][4] = {};
  stageB(0, 0);
  __syncthreads();     // covers conv As writes + Bs[0]
  int cur = 0;
  for (int it = 0; it < 4; ++it) {
    if (it + 1 < 4) stageB(cur ^ 1, it + 1);
    v8s a[4], b[4];
#pragma unroll
    for (int m = 0; m < 4; ++m)
      a[m] = *(const v8s*)&As[wr * 64 + m * 16 + lr][it * 32 + ko];
#pragma unroll
    for (int n = 0; n < 4; ++n)
      b[n] = *(const v8s*)&Bs[cur][(wc * 64 + n * 16 + lr) * 32 + ko];
#pragma unroll
    for (int m = 0; m < 4; ++m)
#pragma unroll
      for (int n = 0; n < 4; ++n)
        acc[m][n] = __builtin_amdgcn_mfma_f32_16x16x32_bf16(a[m], b[n], acc[m][n], 0, 0, 0);
    __syncthreads();
    cur ^= 1;
  }

  size_t zoff = (size_t)blockIdx.z * (size_t)SEQ * DPROJ;
#pragma unroll
  for (int m = 0; m < 4; ++m) {
#pragma unroll
    for (int n = 0; n < 4; ++n) {
      int gc = wc * 64 + n * 16 + lr;
      if (gc >= DPROJ) continue;
      int gr0 = bm + wr * 64 + m * 16 + (lane >> 4) * 4;
#pragma unroll
      for (int j = 0; j < 4; ++j)
        pkb[zoff + (size_t)(gr0 + j) * DPROJ + gc] = f2bf(acc[m][n][j]);
    }
  }
}

// outb[idx] = bf16( sum_p bf2f(part[idx + p*sz]) )
__global__ __launch_bounds__(256) void reduceNb_kernel(
    const ushort_t* __restrict__ part, ushort_t* __restrict__ outb,
    int sz, int nparts) {
  int idx = blockIdx.x * 256 + threadIdx.x;
  if (idx >= sz) return;
  float s = 0.f;
  for (int p = 0; p < nparts; ++p) s += bf2f(part[idx + (size_t)p * sz]);
  outb[idx] = f2bf(s);
}

// Pass A: per-chunk cumulative dA product + local end state (h0 = 0).
__global__ __launch_bounds__(256) void scan_passA_kernel(
    const ushort_t* __restrict__ dtbb, const ushort_t* __restrict__ xcb,
    const ushort_t* __restrict__ dbcb, const float* __restrict__ A_log,
    ushort_t* __restrict__ aprodb, ushort_t* __restrict__ hendb) {
  __shared__ float Bsh[CL][16];
  int c = blockIdx.x;
  int d = blockIdx.y * 256 + threadIdx.x;
  int t0 = c * CL;
  {
    int j = threadIdx.x;           // CL*16/4 = 64 ushort4 slots
    if (j < CL * 4) {
      int r = j >> 2, col = (j & 3) * 4;
      ushort4 v = *(const ushort4*)&dbcb[(size_t)(t0 + r) * DPROJ + DT_RANK + col];
      Bsh[r][col]     = bf2f(v.x);
      Bsh[r][col + 1] = bf2f(v.y);
      Bsh[r][col + 2] = bf2f(v.z);
      Bsh[r][col + 3] = bf2f(v.w);
    }
  }
  float Av[NSTATE], h[NSTATE], ap[NSTATE];
#pragma unroll
  for (int n = 0; n < NSTATE; ++n) {
    Av[n] = -expf(A_log[(size_t)d * NSTATE + n]) * LOG2E;
    h[n] = 0.f;
    ap[n] = 1.f;
  }
  __syncthreads();
#pragma unroll 2
  for (int tt = 0; tt < CL; ++tt) {
    int t = t0 + tt;
    float dtv = bf2f(dtbb[(size_t)t * D_INNER + d]);
    float uv  = bf2f(xcb[(size_t)t * D_INNER + d]);
    float du = dtv * uv;
#pragma unroll
    for (int n = 0; n < NSTATE; ++n) {
      float dA = exp2f(dtv * Av[n]);
      h[n] = fmaf(dA, h[n], du * Bsh[tt][n]);
      ap[n] *= dA;
    }
  }
  size_t base = ((size_t)c * D_INNER + d) * NSTATE;
  u8s oa, ob, ha, hb;
#pragma unroll
  for (int n = 0; n < 8; ++n) {
    oa[n] = f2bf(ap[n]);     ob[n] = f2bf(ap[n + 8]);
    ha[n] = f2bf(h[n]);      hb[n] = f2bf(h[n + 8]);
  }
  *(u8s*)&aprodb[base] = oa;     *(u8s*)&aprodb[base + 8] = ob;
  *(u8s*)&hendb[base]  = ha;     *(u8s*)&hendb[base + 8]  = hb;
}

// Pass B: carry across 128 chunks (bf16 state in/out).
__global__ __launch_bounds__(256) void scan_passB_kernel(
    const ushort_t* __restrict__ aprodb, ushort_t* __restrict__ hendb) {
  int tid = threadIdx.x;
  int lane = tid & 63;
  int wave = tid >> 6;
  int seg = lane >> 4;                       // 0..3
  int chain = blockIdx.x * 64 + wave * 16 + (lane & 15);
  const size_t stride = (size_t)D_INNER * NSTATE;
  float a[SCAN_CPS], e[SCAN_CPS];
  float P = 1.f, E = 0.f;
  int c0 = seg * SCAN_CPS;
#pragma unroll
  for (int j = 0; j < SCAN_CPS; ++j) {
    a[j] = bf2f(aprodb[(size_t)(c0 + j) * stride + chain]);
    e[j] = bf2f(hendb[(size_t)(c0 + j) * stride + chain]);
    E = fmaf(a[j], E, e[j]);
    P *= a[j];
  }
#pragma unroll
  for (int dstep = 1; dstep < SCAN_SEGS; dstep <<= 1) {
    float Pp = __shfl_up(P, dstep * 16);
    float Ep = __shfl_up(E, dstep * 16);
    if (seg >= dstep) { E = fmaf(P, Ep, E); P *= Pp; }
  }
  float Ex = __shfl_up(E, 16);
  if (seg == 0) Ex = 0.f;
  float h = Ex;
#pragma unroll
  for (int j = 0; j < SCAN_CPS; ++j) {
    hendb[(size_t)(c0 + j) * stride + chain] = f2bf(h);
    h = fmaf(a[j], h, e[j]);
  }
}

// Pass C: rescan from bf16 hin; y = (scan + u*D) * silu(z) -> bf16.
// z comes from the TWO in_proj partials (summed).
__global__ __launch_bounds__(256) void scan_passC_kernel(
    const ushort_t* __restrict__ dtbb, const ushort_t* __restrict__ xcb,
    const ushort_t* __restrict__ dbcb, const float* __restrict__ A_log,
    const float* __restrict__ Dp, const ushort_t* __restrict__ xzp,
    const ushort_t* __restrict__ hinb, ushort_t* __restrict__ yb) {
  __shared__ float BCsh[CL][32];   // [tt][0..15]=B, [16..31]=C
  int c = blockIdx.x;
  int d = blockIdx.y * 256 + threadIdx.x;
  int t0 = c * CL;
  {
    int j = threadIdx.x;           // CL*32/4 = 128 ushort4 slots
    if (j < CL * 8) {
      int r = j >> 3, col = (j & 7) * 4;
      ushort4 v = *(const ushort4*)&dbcb[(size_t)(t0 + r) * DPROJ + DT_RANK + col];
      BCsh[r][col]     = bf2f(v.x);
      BCsh[r][col + 1] = bf2f(v.y);
      BCsh[r][col + 2] = bf2f(v.z);
      BCsh[r][col + 3] = bf2f(v.w);
    }
  }
  float Av[NSTATE], h[NSTATE];
  size_t base = ((size_t)c * D_INNER + d) * NSTATE;
  u8s h0 = *(const u8s*)&hinb[base];
  u8s h1 = *(const u8s*)&hinb[base + 8];
#pragma unroll
  for (int n = 0; n < NSTATE; ++n) {
    Av[n] = -expf(A_log[(size_t)d * NSTATE + n]) * LOG2E;
    h[n] = (n < 8) ? bf2f(h0[n & 7]) : bf2f(h1[n & 7]);
  }
  float Dv = Dp[d];
  __syncthreads();
#pragma unroll 2
  for (int tt = 0; tt < CL; ++tt) {
    int t = t0 + tt;
    float dtv = bf2f(dtbb[(size_t)t * D_INNER + d]);
    float uv  = bf2f(xcb[(size_t)t * D_INNER + d]);
    float du = dtv * uv;
    float yv = 0.f;
#pragma unroll
    for (int n = 0; n < NSTATE; ++n) {
      float dA = exp2f(dtv * Av[n]);
      h[n] = fmaf(dA, h[n], du * BCsh[tt][n]);
      yv = fmaf(h[n], BCsh[tt][16 + n], yv);
    }
    size_t zi = (size_t)t * 4096 + D_INNER + d;
    float zv = bf2f(xzp[zi]) + bf2f(xzp[XZP1 + zi]);
    yb[(size_t)t * D_INNER + d] = f2bf((yv + uv * Dv) * silu_f(zv));
  }
}

extern "C" void kernel_launch(void* const* d_in, const int* in_sizes, int n_in,
                              void* d_out, int out_size, void* d_ws, size_t ws_size,
                              hipStream_t stream) {
  const float* h_in   = (const float*)d_in[0];
  const float* norm_w = (const float*)d_in[1];
  const float* in_w   = (const float*)d_in[2];
  const float* conv_w = (const float*)d_in[3];
  const float* conv_b = (const float*)d_in[4];
  const float* xp_w   = (const float*)d_in[5];
  const float* dt_w   = (const float*)d_in[6];
  const float* dt_b   = (const float*)d_in[7];
  const float* A_log  = (const float*)d_in[8];
  const float* Dp     = (const float*)d_in[9];
  const float* out_w  = (const float*)d_in[10];
  const float* normf  = (const float*)d_in[11];
  float* out = (float*)d_out;

  float* ws = (float*)d_ws;
  const size_t TD = (size_t)SEQ * D_MODEL;            // 2.10M
  const size_t TI = (size_t)SEQ * D_INNER;            // 4.19M
  const size_t ST = (size_t)NCH * D_INNER * NSTATE;   // 4.19M elements
  const size_t DB = (size_t)SEQ * DPROJ;
  const size_t INW = (size_t)2 * D_INNER * D_MODEL;
  const size_t XPW = (size_t)DPROJ * D_INNER;
  const size_t DTW = (size_t)D_INNER * DT_RANK;
  const size_t OUW = (size_t)D_MODEL * D_INNER;

  float* res = ws; ws += TD;
  ushort_t* us = (ushort_t*)ws;
  ushort_t* pkb    = us;  us += 8 * TD;   // out_proj 8 partials / x_proj 16 partials
  ushort_t* aprodb = us;  us += ST;
  ushort_t* hendb  = us;  us += ST;       // hin after passB
  ushort_t* hnb    = us;  us += TD;
  ushort_t* xzp    = us;  us += 4 * TI;   // in_proj split-K=2 partials
  ushort_t* xcb    = us;  us += TI;
  ushort_t* dtbb   = us;  us += TI;
  ushort_t* ybf    = us;  us += TI;
  ushort_t* dbcb   = us;  us += DB;
  ushort_t* inwb   = us;  us += 2 * INW;
  ushort_t* xpwb   = us;  us += 2 * XPW;
  ushort_t* dtwb   = us;  us += 2 * DTW;
  ushort_t* ouwb   = us;  us += 2 * OUW;

  // convert ALL weights (both layers) in one dispatch
  {
    int n0 = (int)(2 * INW / 4), n1 = (int)(2 * XPW / 4);
    int n2 = (int)(2 * DTW / 4), n3 = (int)(2 * OUW / 4);
    int tot = n0 + n1 + n2 + n3;
    f2bf_all_kernel<<<(tot + 255) / 256, 256, 0, stream>>>(
        in_w, inwb, n0, xp_w, xpwb, n1, dt_w, dtwb, n2, out_w, ouwb, n3);
  }

  for (int i = 0; i < 2; ++i) {
    // residual update + rmsnorm; layer>0 consumes bf16 out_proj split-K=8 partials
    addrms_kernel<<<SEQ, 256, 0, stream>>>(
        h_in, i == 0 ? nullptr : pkb, 8,
        i == 0 ? nullptr : res,
        norm_w + (size_t)i * D_MODEL, res, nullptr, hnb);
    // in_proj: split-K=2 -> xzp (two bf16 partials of [2048 x 4096])
    gemm_bt<2, false, 2><<<dim3(32, 16, 2), 256, 0, stream>>>(
        hnb, inwb + (size_t)i * INW, xzp, nullptr,
        SEQ, 2 * D_INNER, D_MODEL, D_MODEL, D_MODEL, 2 * D_INNER);
    // fused conv+silu (-> xcb) + x_proj K-slice GEMM (-> pkb bf16 partials x16)
    convxproj_kernel<<<dim3(1, 16, 16), 256, 0, stream>>>(
        xzp, conv_w + (size_t)i * D_INNER * 4, conv_b + (size_t)i * D_INNER,
        xpwb + (size_t)i * XPW, xcb, pkb);
    reduceNb_kernel<<<(DB + 255) / 256, 256, 0, stream>>>(pkb, dbcb, (int)DB, 16);
    // dt_proj -> softplus -> dtbb (bf16)
    gemm_bt<1, false, 1><<<dim3(16, 16, 1), 256, 0, stream>>>(
        dbcb, dtwb + (size_t)i * DTW, dtbb, dt_b + (size_t)i * D_INNER,
        SEQ, D_INNER, DT_RANK, DPROJ, DT_RANK, D_INNER);
    // scan: A -> B -> C (3 dispatches, bf16 state)
    scan_passA_kernel<<<dim3(NCH, D_INNER / 256), 256, 0, stream>>>(
        dtbb, xcb, dbcb, A_log + (size_t)i * D_INNER * NSTATE, aprodb, hendb);
    scan_passB_kernel<<<(D_INNER * NSTATE) / 64, 256, 0, stream>>>(aprodb, hendb);
    scan_passC_kernel<<<dim3(NCH, D_INNER / 256), 256, 0, stream>>>(
        dtbb, xcb, dbcb, A_log + (size_t)i * D_INNER * NSTATE,
        Dp + (size_t)i * D_INNER, xzp, hendb, ybf);
    // out_proj: split-K=8 -> pkb (bf16 partials, 8 x TD)
    gemm_bt<8, false, 2><<<dim3(8, 16, 8), 256, 0, stream>>>(
        ybf, ouwb + (size_t)i * OUW, pkb, nullptr,
        SEQ, D_MODEL, D_INNER, D_INNER, D_INNER, D_MODEL);
  }
  addrms_kernel<<<SEQ, 256, 0, stream>>>(
      h_in, pkb, 8, res, normf, nullptr, out, nullptr);
}

// Round 16
// 342.029 us; speedup vs baseline: 1.0774x; 1.0774x over previous
//
#include <hip/hip_runtime.h>
#include <math.h>

#define D_MODEL 1024
#define D_INNER 2048
#define DPROJ   96      // DT_RANK + 2*D_STATE
#define DT_RANK 64
#define NSTATE  16
#define SEQ     2048
#define CL      16      // chunk length for scan
#define NCH     (SEQ/CL)            // 128
#define SCAN_SEGS 4
#define SCAN_CPS  (NCH / SCAN_SEGS) // 32 chunks per segment-lane
#define LOG2E   1.44269504088896340736f
#define TDC     ((size_t)SEQ * D_MODEL)   // compile-time TD stride for partials

typedef unsigned short ushort_t;
typedef short v8s __attribute__((ext_vector_type(8)));
typedef unsigned short u8s __attribute__((ext_vector_type(8)));
typedef float v4f __attribute__((ext_vector_type(4)));
typedef __attribute__((address_space(3))) unsigned int as3_u32;
typedef __attribute__((address_space(1))) unsigned int as1_u32;

__device__ __forceinline__ float silu_f(float x) { return x / (1.f + expf(-x)); }

__device__ __forceinline__ ushort_t f2bf(float f) {
  union { float f; unsigned u; } x; x.f = f;
  unsigned r = x.u + 0x7fffu + ((x.u >> 16) & 1u);  // RNE; inputs finite
  return (ushort_t)(r >> 16);
}
__device__ __forceinline__ float bf2f(ushort_t b) {
  union { unsigned u; float f; } x; x.u = ((unsigned)b) << 16; return x.f;
}

// async global->LDS, 16B per lane; lds dest = wave-uniform base + lane*16
__device__ __forceinline__ void gl_lds16(const ushort_t* g, ushort_t* l) {
  __builtin_amdgcn_global_load_lds((const as1_u32*)g, (as3_u32*)l, 16, 0, 0);
}

// x = (pN ? sum of nparts bf16 partials : a) (+ b); res_out = x;
// xn = rmsnorm(x)*w -> f32 (xnf) and/or bf16 (xnb)
__global__ __launch_bounds__(256) void addrms_kernel(
    const float* __restrict__ a, const ushort_t* __restrict__ pN, int nparts,
    const float* __restrict__ b,
    const float* __restrict__ w, float* __restrict__ res_out,
    float* __restrict__ xnf, ushort_t* __restrict__ xnb) {
  int t = blockIdx.x;
  int tid = threadIdx.x;
  float v[4];
  float ss = 0.f;
#pragma unroll
  for (int j = 0; j < 4; ++j) {
    int dcol = tid + j * 256;
    size_t off = (size_t)t * D_MODEL + dcol;
    float x;
    if (pN) {
      x = 0.f;
      for (int p = 0; p < nparts; ++p) x += bf2f(pN[off + (size_t)p * TDC]);
    } else {
      x = a[off];
    }
    if (b) x += b[off];
    v[j] = x;
    ss += x * x;
  }
#pragma unroll
  for (int off = 32; off > 0; off >>= 1) ss += __shfl_down(ss, off);
  __shared__ float red[4];
  __shared__ float rmsv;
  int wid = tid >> 6, lane = tid & 63;
  if (lane == 0) red[wid] = ss;
  __syncthreads();
  if (tid == 0) {
    float s = red[0] + red[1] + red[2] + red[3];
    rmsv = rsqrtf(s / (float)D_MODEL + 1e-5f);
  }
  __syncthreads();
  float r = rmsv;
#pragma unroll
  for (int j = 0; j < 4; ++j) {
    int dcol = tid + j * 256;
    if (res_out) res_out[(size_t)t * D_MODEL + dcol] = v[j];
    float xn = v[j] * r * w[dcol];
    if (xnf) xnf[(size_t)t * D_MODEL + dcol] = xn;
    if (xnb) xnb[(size_t)t * D_MODEL + dcol] = f2bf(xn);
  }
}

// single-dispatch f32->bf16 of all 4 weight tensors (both layers each)
__global__ __launch_bounds__(256) void f2bf_all_kernel(
    const float* __restrict__ s0, ushort_t* __restrict__ d0, int n0,
    const float* __restrict__ s1, ushort_t* __restrict__ d1, int n1,
    const float* __restrict__ s2, ushort_t* __restrict__ d2, int n2,
    const float* __restrict__ s3, ushort_t* __restrict__ d3, int n3) {
  int j = blockIdx.x * 256 + threadIdx.x;
  const float* s; ushort_t* d;
  if (j < n0) { s = s0; d = d0; }
  else {
    j -= n0;
    if (j < n1) { s = s1; d = d1; }
    else {
      j -= n1;
      if (j < n2) { s = s2; d = d2; }
      else {
        j -= n2;
        if (j >= n3) return;
        s = s3; d = d3;
      }
    }
  }
  float4 v = ((const float4*)s)[j];
  ushort4 o;
  o.x = f2bf(v.x); o.y = f2bf(v.y); o.z = f2bf(v.z); o.w = f2bf(v.w);
  ((ushort4*)d)[j] = o;
}

// ------------- bf16 MFMA GEMM (NT): C[m,n] = sum_k A[m,k]*B[n,k] -------------
// m97 structure + double-buffered prefetch; one __syncthreads per K-step.
// XCD-aware bijective block swizzle (m204). SPLITK>1: partials at z*M*ldc.
// EPI: 0 = f32 out, 1 = softplus(acc+bias[col]) -> bf16, 2 = bf16.
template <int SPLITK, bool CLAMPN, int EPI>
__global__ __launch_bounds__(256) void gemm_bt(
    const ushort_t* __restrict__ A, const ushort_t* __restrict__ B,
    void* __restrict__ Cv, const float* __restrict__ bias,
    int M, int N, int K, int lda, int ldb, int ldc) {
  __shared__ ushort_t As[2][128 * 32];
  __shared__ ushort_t Bs[2][128 * 32];
  int tid = threadIdx.x;

  // bijective XCD swizzle of the flattened block id
  int gx = gridDim.x, gy = gridDim.y;
  int nwg = gx * gy * gridDim.z;
  int phys = blockIdx.x + gx * (blockIdx.y + gy * blockIdx.z);
  int q = nwg >> 3, r = nwg & 7;
  int xcd = phys & 7, idx8 = phys >> 3;
  int lbid = (xcd < r ? xcd * (q + 1) : r * (q + 1) + (xcd - r) * q) + idx8;
  int bx = lbid % gx, by = (lbid / gx) % gy, bz = lbid / (gx * gy);

  int bm = by * 128;
  int bn = bx * 128;
  int kchunk = K / SPLITK;
  int k0 = bz * kchunk;
  int nk = kchunk / 32;

  int lane = tid & 63, wid = tid >> 6;
  int wr = wid >> 1, wc = wid & 1;
  int lr = lane & 15;
  int ko = (lane >> 4) * 8;

  int rs0 = wid * 16 + (lane >> 2);
  int segc = (lane & 3) * 8;

  auto stage = [&](int buf, int kt) {
#pragma unroll
    for (int s = 0; s < 2; ++s) {
      int r2 = s * 64 + rs0;
      int cc = kt + segc;
      gl_lds16(A + (size_t)(bm + r2) * lda + cc, &As[buf][s * 2048 + wid * 512]);
      int bc = bn + r2;
      if (CLAMPN) bc = min(bc, N - 1);   // in-bounds; junk cols never stored
      gl_lds16(B + (size_t)bc * ldb + cc, &Bs[buf][s * 2048 + wid * 512]);
    }
  };

  v4f acc[4][4] = {};

  stage(0, k0);
  __syncthreads();
  int cur = 0;
  for (int it = 0; it < nk; ++it) {
    if (it + 1 < nk) stage(cur ^ 1, k0 + (it + 1) * 32);
    v8s a[4], b[4];
#pragma unroll
    for (int m = 0; m < 4; ++m)
      a[m] = *(const v8s*)&As[cur][(wr * 64 + m * 16 + lr) * 32 + ko];
#pragma unroll
    for (int n = 0; n < 4; ++n)
      b[n] = *(const v8s*)&Bs[cur][(wc * 64 + n * 16 + lr) * 32 + ko];
#pragma unroll
    for (int m = 0; m < 4; ++m)
#pragma unroll
      for (int n = 0; n < 4; ++n)
        acc[m][n] = __builtin_amdgcn_mfma_f32_16x16x32_bf16(a[m], b[n], acc[m][n], 0, 0, 0);
    __syncthreads();
    cur ^= 1;
  }

  float* Cf = (float*)Cv;
  ushort_t* Cb = (ushort_t*)Cv;
  size_t zoff = (SPLITK > 1) ? (size_t)bz * (size_t)M * (size_t)ldc : 0;

#pragma unroll
  for (int m = 0; m < 4; ++m) {
#pragma unroll
    for (int n = 0; n < 4; ++n) {
      int gc = bn + wc * 64 + n * 16 + lr;
      if (gc >= N) continue;
      int gr0 = bm + wr * 64 + m * 16 + (lane >> 4) * 4;
      float bv = (EPI == 1) ? bias[gc] : 0.f;
#pragma unroll
      for (int j = 0; j < 4; ++j) {
        float val = acc[m][n][j];
        size_t idx = zoff + (size_t)(gr0 + j) * ldc + gc;
        if (EPI == 0) {
          Cf[idx] = val;
        } else if (EPI == 1) {
          float x = val + bv;
          x = fmaxf(x, 0.f) + log1pf(expf(-fabsf(x)));
          Cb[idx] = f2bf(x);
        } else {
          Cb[idx] = f2bf(val);
        }
      }
    }
  }
}

// ---------- fused conv_silu + x_proj K-slice GEMM ----------
// grid (1, 16 M-tiles, 16 K-slices). Block (by,bz):
//  phase 1: conv+silu for t in [bm,bm+128), c in [bz*128,bz*128+128)
//           -> LDS A-tile [128][136] (padded, 16B rows) AND global xcb.
//  phase 2: 128x96 GEMM vs xpwb rows, K-slice of 128, A from resident LDS,
//           B double-buffered via global_load_lds; bf16 partial out.
__global__ __launch_bounds__(256) void convxproj_kernel(
    const ushort_t* __restrict__ xzb, const float* __restrict__ cw,
    const float* __restrict__ cb, const ushort_t* __restrict__ Bw,
    ushort_t* __restrict__ xcb, ushort_t* __restrict__ pkb) {
  __shared__ ushort_t As[128][136];   // 272B rows: 16B-aligned, 2-way banks
  __shared__ ushort_t Bs[2][128 * 32];
  int tid = threadIdx.x;
  int bm = blockIdx.y * 128;
  int c0s = blockIdx.z * 128;         // channel / K-slice offset
  int k0 = c0s;

  // ---- phase 1: conv ----
  {
    int quad = tid & 31;              // 4 channels each
    int tg = tid >> 5;                // 8 groups x 16 t
    int cc = c0s + quad * 4;
    int tbase = bm + tg * 16;
    float4 cbv = *(const float4*)&cb[cc];
    float4 wv[4];
#pragma unroll
    for (int i = 0; i < 4; ++i) wv[i] = *(const float4*)&cw[(cc + i) * 4];
    float rw[4][4];                   // ring of last 4 rows (compile-time idx)
#pragma unroll
    for (int p = 0; p < 3; ++p) {
      int ts = tbase - 3 + p;
      if (ts < 0) {
        rw[p][0] = rw[p][1] = rw[p][2] = rw[p][3] = 0.f;
      } else {
        ushort4 x = *(const ushort4*)&xzb[(size_t)ts * 4096 + cc];
        rw[p][0] = bf2f(x.x); rw[p][1] = bf2f(x.y);
        rw[p][2] = bf2f(x.z); rw[p][3] = bf2f(x.w);
      }
    }
#pragma unroll
    for (int j = 0; j < 16; ++j) {
      int t = tbase + j;
      {
        ushort4 x = *(const ushort4*)&xzb[(size_t)t * 4096 + cc];
        rw[(3 + j) & 3][0] = bf2f(x.x); rw[(3 + j) & 3][1] = bf2f(x.y);
        rw[(3 + j) & 3][2] = bf2f(x.z); rw[(3 + j) & 3][3] = bf2f(x.w);
      }
      float acc[4] = {cbv.x, cbv.y, cbv.z, cbv.w};
#pragma unroll
      for (int k = 0; k < 4; ++k) {
#pragma unroll
        for (int i = 0; i < 4; ++i)
          acc[i] = fmaf(rw[(j + k) & 3][i], ((const float*)&wv[i])[k], acc[i]);
      }
      ushort4 o;
      o.x = f2bf(silu_f(acc[0]));
      o.y = f2bf(silu_f(acc[1]));
      o.z = f2bf(silu_f(acc[2]));
      o.w = f2bf(silu_f(acc[3]));
      *(ushort4*)&As[tg * 16 + j][quad * 4] = o;
      *(ushort4*)&xcb[(size_t)t * D_INNER + cc] = o;
    }
  }

  // ---- phase 2: GEMM (A resident in LDS) ----
  int lane = tid & 63, wid = tid >> 6;
  int wr = wid >> 1, wc = wid & 1;
  int lr = lane & 15;
  int ko = (lane >> 4) * 8;
  int rs0 = wid * 16 + (lane >> 2);
  int segc = (lane & 3) * 8;

  auto stageB = [&](int buf, int it) {
#pragma unroll
    for (int s = 0; s < 2; ++s) {
      int r2 = s * 64 + rs0;
      int bc = min(r2, DPROJ - 1);
      int cc2 = k0 + it * 32 + segc;
      gl_lds16(Bw + (size_t)bc * D_INNER + cc2, &Bs[buf][s * 2048 + wid * 512]);
    }
  };

  v4f acc[4][4] = {};
  stageB(0, 0);
  __syncthreads();     // covers conv As writes + Bs[0]
  int cur = 0;
  for (int it = 0; it < 4; ++it) {
    if (it + 1 < 4) stageB(cur ^ 1, it + 1);
    v8s a[4], b[4];
#pragma unroll
    for (int m = 0; m < 4; ++m)
      a[m] = *(const v8s*)&As[wr * 64 + m * 16 + lr][it * 32 + ko];
#pragma unroll
    for (int n = 0; n < 4; ++n)
      b[n] = *(const v8s*)&Bs[cur][(wc * 64 + n * 16 + lr) * 32 + ko];
#pragma unroll
    for (int m = 0; m < 4; ++m)
#pragma unroll
      for (int n = 0; n < 4; ++n)
        acc[m][n] = __builtin_amdgcn_mfma_f32_16x16x32_bf16(a[m], b[n], acc[m][n], 0, 0, 0);
    __syncthreads();
    cur ^= 1;
  }

  size_t zoff = (size_t)blockIdx.z * (size_t)SEQ * DPROJ;
#pragma unroll
  for (int m = 0; m < 4; ++m) {
#pragma unroll
    for (int n = 0; n < 4; ++n) {
      int gc = wc * 64 + n * 16 + lr;
      if (gc >= DPROJ) continue;
      int gr0 = bm + wr * 64 + m * 16 + (lane >> 4) * 4;
#pragma unroll
      for (int j = 0; j < 4; ++j)
        pkb[zoff + (size_t)(gr0 + j) * DPROJ + gc] = f2bf(acc[m][n][j]);
    }
  }
}

// outb[idx] = bf16( sum_p bf2f(part[idx + p*sz]) )
__global__ __launch_bounds__(256) void reduceNb_kernel(
    const ushort_t* __restrict__ part, ushort_t* __restrict__ outb,
    int sz, int nparts) {
  int idx = blockIdx.x * 256 + threadIdx.x;
  if (idx >= sz) return;
  float s = 0.f;
  for (int p = 0; p < nparts; ++p) s += bf2f(part[idx + (size_t)p * sz]);
  outb[idx] = f2bf(s);
}

// Pass A: per-chunk cumulative dA product + local end state (h0 = 0).
__global__ __launch_bounds__(256) void scan_passA_kernel(
    const ushort_t* __restrict__ dtbb, const ushort_t* __restrict__ xcb,
    const ushort_t* __restrict__ dbcb, const float* __restrict__ A_log,
    ushort_t* __restrict__ aprodb, ushort_t* __restrict__ hendb) {
  __shared__ float Bsh[CL][16];
  int c = blockIdx.x;
  int d = blockIdx.y * 256 + threadIdx.x;
  int t0 = c * CL;
  {
    int j = threadIdx.x;           // CL*16/4 = 64 ushort4 slots
    if (j < CL * 4) {
      int r = j >> 2, col = (j & 3) * 4;
      ushort4 v = *(const ushort4*)&dbcb[(size_t)(t0 + r) * DPROJ + DT_RANK + col];
      Bsh[r][col]     = bf2f(v.x);
      Bsh[r][col + 1] = bf2f(v.y);
      Bsh[r][col + 2] = bf2f(v.z);
      Bsh[r][col + 3] = bf2f(v.w);
    }
  }
  float Av[NSTATE], h[NSTATE], ap[NSTATE];
#pragma unroll
  for (int n = 0; n < NSTATE; ++n) {
    Av[n] = -expf(A_log[(size_t)d * NSTATE + n]) * LOG2E;
    h[n] = 0.f;
    ap[n] = 1.f;
  }
  __syncthreads();
#pragma unroll 2
  for (int tt = 0; tt < CL; ++tt) {
    int t = t0 + tt;
    float dtv = bf2f(dtbb[(size_t)t * D_INNER + d]);
    float uv  = bf2f(xcb[(size_t)t * D_INNER + d]);
    float du = dtv * uv;
#pragma unroll
    for (int n = 0; n < NSTATE; ++n) {
      float dA = exp2f(dtv * Av[n]);
      h[n] = fmaf(dA, h[n], du * Bsh[tt][n]);
      ap[n] *= dA;
    }
  }
  size_t base = ((size_t)c * D_INNER + d) * NSTATE;
  u8s oa, ob, ha, hb;
#pragma unroll
  for (int n = 0; n < 8; ++n) {
    oa[n] = f2bf(ap[n]);     ob[n] = f2bf(ap[n + 8]);
    ha[n] = f2bf(h[n]);      hb[n] = f2bf(h[n + 8]);
  }
  *(u8s*)&aprodb[base] = oa;     *(u8s*)&aprodb[base + 8] = ob;
  *(u8s*)&hendb[base]  = ha;     *(u8s*)&hendb[base + 8]  = hb;
}

// Pass B: carry across 128 chunks (bf16 state in/out).
__global__ __launch_bounds__(256) void scan_passB_kernel(
    const ushort_t* __restrict__ aprodb, ushort_t* __restrict__ hendb) {
  int tid = threadIdx.x;
  int lane = tid & 63;
  int wave = tid >> 6;
  int seg = lane >> 4;                       // 0..3
  int chain = blockIdx.x * 64 + wave * 16 + (lane & 15);
  const size_t stride = (size_t)D_INNER * NSTATE;
  float a[SCAN_CPS], e[SCAN_CPS];
  float P = 1.f, E = 0.f;
  int c0 = seg * SCAN_CPS;
#pragma unroll
  for (int j = 0; j < SCAN_CPS; ++j) {
    a[j] = bf2f(aprodb[(size_t)(c0 + j) * stride + chain]);
    e[j] = bf2f(hendb[(size_t)(c0 + j) * stride + chain]);
    E = fmaf(a[j], E, e[j]);
    P *= a[j];
  }
#pragma unroll
  for (int dstep = 1; dstep < SCAN_SEGS; dstep <<= 1) {
    float Pp = __shfl_up(P, dstep * 16);
    float Ep = __shfl_up(E, dstep * 16);
    if (seg >= dstep) { E = fmaf(P, Ep, E); P *= Pp; }
  }
  float Ex = __shfl_up(E, 16);
  if (seg == 0) Ex = 0.f;
  float h = Ex;
#pragma unroll
  for (int j = 0; j < SCAN_CPS; ++j) {
    hendb[(size_t)(c0 + j) * stride + chain] = f2bf(h);
    h = fmaf(a[j], h, e[j]);
  }
}

// Pass C: rescan from bf16 hin; y = (scan + u*D) * silu(z) -> bf16.
__global__ __launch_bounds__(256) void scan_passC_kernel(
    const ushort_t* __restrict__ dtbb, const ushort_t* __restrict__ xcb,
    const ushort_t* __restrict__ dbcb, const float* __restrict__ A_log,
    const float* __restrict__ Dp, const ushort_t* __restrict__ xzb,
    const ushort_t* __restrict__ hinb, ushort_t* __restrict__ yb) {
  __shared__ float BCsh[CL][32];   // [tt][0..15]=B, [16..31]=C
  int c = blockIdx.x;
  int d = blockIdx.y * 256 + threadIdx.x;
  int t0 = c * CL;
  {
    int j = threadIdx.x;           // CL*32/4 = 128 ushort4 slots
    if (j < CL * 8) {
      int r = j >> 3, col = (j & 7) * 4;
      ushort4 v = *(const ushort4*)&dbcb[(size_t)(t0 + r) * DPROJ + DT_RANK + col];
      BCsh[r][col]     = bf2f(v.x);
      BCsh[r][col + 1] = bf2f(v.y);
      BCsh[r][col + 2] = bf2f(v.z);
      BCsh[r][col + 3] = bf2f(v.w);
    }
  }
  float Av[NSTATE], h[NSTATE];
  size_t base = ((size_t)c * D_INNER + d) * NSTATE;
  u8s h0 = *(const u8s*)&hinb[base];
  u8s h1 = *(const u8s*)&hinb[base + 8];
#pragma unroll
  for (int n = 0; n < NSTATE; ++n) {
    Av[n] = -expf(A_log[(size_t)d * NSTATE + n]) * LOG2E;
    h[n] = (n < 8) ? bf2f(h0[n & 7]) : bf2f(h1[n & 7]);
  }
  float Dv = Dp[d];
  __syncthreads();
#pragma unroll 2
  for (int tt = 0; tt < CL; ++tt) {
    int t = t0 + tt;
    float dtv = bf2f(dtbb[(size_t)t * D_INNER + d]);
    float uv  = bf2f(xcb[(size_t)t * D_INNER + d]);
    float du = dtv * uv;
    float yv = 0.f;
#pragma unroll
    for (int n = 0; n < NSTATE; ++n) {
      float dA = exp2f(dtv * Av[n]);
      h[n] = fmaf(dA, h[n], du * BCsh[tt][n]);
      yv = fmaf(h[n], BCsh[tt][16 + n], yv);
    }
    float zv = bf2f(xzb[(size_t)t * 4096 + D_INNER + d]);
    yb[(size_t)t * D_INNER + d] = f2bf((yv + uv * Dv) * silu_f(zv));
  }
}

extern "C" void kernel_launch(void* const* d_in, const int* in_sizes, int n_in,
                              void* d_out, int out_size, void* d_ws, size_t ws_size,
                              hipStream_t stream) {
  const float* h_in   = (const float*)d_in[0];
  const float* norm_w = (const float*)d_in[1];
  const float* in_w   = (const float*)d_in[2];
  const float* conv_w = (const float*)d_in[3];
  const float* conv_b = (const float*)d_in[4];
  const float* xp_w   = (const float*)d_in[5];
  const float* dt_w   = (const float*)d_in[6];
  const float* dt_b   = (const float*)d_in[7];
  const float* A_log  = (const float*)d_in[8];
  const float* Dp     = (const float*)d_in[9];
  const float* out_w  = (const float*)d_in[10];
  const float* normf  = (const float*)d_in[11];
  float* out = (float*)d_out;

  float* ws = (float*)d_ws;
  const size_t TD = (size_t)SEQ * D_MODEL;            // 2.10M
  const size_t TI = (size_t)SEQ * D_INNER;            // 4.19M
  const size_t ST = (size_t)NCH * D_INNER * NSTATE;   // 4.19M elements
  const size_t DB = (size_t)SEQ * DPROJ;
  const size_t INW = (size_t)2 * D_INNER * D_MODEL;
  const size_t XPW = (size_t)DPROJ * D_INNER;
  const size_t DTW = (size_t)D_INNER * DT_RANK;
  const size_t OUW = (size_t)D_MODEL * D_INNER;

  float* res = ws; ws += TD;
  ushort_t* us = (ushort_t*)ws;
  ushort_t* pkb    = us;  us += 4 * TD;   // out_proj 4 partials / x_proj 16 partials
  ushort_t* aprodb = us;  us += ST;
  ushort_t* hendb  = us;  us += ST;       // hin after passB
  ushort_t* hnb    = us;  us += TD;
  ushort_t* xzb    = us;  us += 2 * TI;
  ushort_t* xcb    = us;  us += TI;
  ushort_t* dtbb   = us;  us += TI;
  ushort_t* ybf    = us;  us += TI;
  ushort_t* dbcb   = us;  us += DB;
  ushort_t* inwb   = us;  us += 2 * INW;
  ushort_t* xpwb   = us;  us += 2 * XPW;
  ushort_t* dtwb   = us;  us += 2 * DTW;
  ushort_t* ouwb   = us;  us += 2 * OUW;

  // convert ALL weights (both layers) in one dispatch
  {
    int n0 = (int)(2 * INW / 4), n1 = (int)(2 * XPW / 4);
    int n2 = (int)(2 * DTW / 4), n3 = (int)(2 * OUW / 4);
    int tot = n0 + n1 + n2 + n3;
    f2bf_all_kernel<<<(tot + 255) / 256, 256, 0, stream>>>(
        in_w, inwb, n0, xp_w, xpwb, n1, dt_w, dtwb, n2, out_w, ouwb, n3);
  }

  for (int i = 0; i < 2; ++i) {
    // residual update + rmsnorm; layer>0 consumes bf16 out_proj split-K=4 partials
    addrms_kernel<<<SEQ, 256, 0, stream>>>(
        h_in, i == 0 ? nullptr : pkb, 4,
        i == 0 ? nullptr : res,
        norm_w + (size_t)i * D_MODEL, res, nullptr, hnb);
    // in_proj: [2048 x 1024] x [4096 x 1024]^T -> xzb (bf16)
    gemm_bt<1, false, 2><<<dim3(32, 16, 1), 256, 0, stream>>>(
        hnb, inwb + (size_t)i * INW, xzb, nullptr,
        SEQ, 2 * D_INNER, D_MODEL, D_MODEL, D_MODEL, 2 * D_INNER);
    // fused conv+silu (-> xcb) + x_proj K-slice GEMM (-> pkb bf16 partials x16)
    convxproj_kernel<<<dim3(1, 16, 16), 256, 0, stream>>>(
        xzb, conv_w + (size_t)i * D_INNER * 4, conv_b + (size_t)i * D_INNER,
        xpwb + (size_t)i * XPW, xcb, pkb);
    reduceNb_kernel<<<(DB + 255) / 256, 256, 0, stream>>>(pkb, dbcb, (int)DB, 16);
    // dt_proj -> softplus -> dtbb (bf16)
    gemm_bt<1, false, 1><<<dim3(16, 16, 1), 256, 0, stream>>>(
        dbcb, dtwb + (size_t)i * DTW, dtbb, dt_b + (size_t)i * D_INNER,
        SEQ, D_INNER, DT_RANK, DPROJ, DT_RANK, D_INNER);
    // scan: A -> B -> C (3 dispatches, bf16 state)
    scan_passA_kernel<<<dim3(NCH, D_INNER / 256), 256, 0, stream>>>(
        dtbb, xcb, dbcb, A_log + (size_t)i * D_INNER * NSTATE, aprodb, hendb);
    scan_passB_kernel<<<(D_INNER * NSTATE) / 64, 256, 0, stream>>>(aprodb, hendb);
    scan_passC_kernel<<<dim3(NCH, D_INNER / 256), 256, 0, stream>>>(
        dtbb, xcb, dbcb, A_log + (size_t)i * D_INNER * NSTATE,
        Dp + (size_t)i * D_INNER, xzb, hendb, ybf);
    // out_proj: split-K=4 -> pkb (bf16 partials, 4 x TD)
    gemm_bt<4, false, 2><<<dim3(8, 16, 4), 256, 0, stream>>>(
        ybf, ouwb + (size_t)i * OUW, pkb, nullptr,
        SEQ, D_MODEL, D_INNER, D_INNER, D_INNER, D_MODEL);
  }
  addrms_kernel<<<SEQ, 256, 0, stream>>>(
      h_in, pkb, 4, res, normf, nullptr, out, nullptr);
}

// Round 17
// 325.502 us; speedup vs baseline: 1.1321x; 1.0508x over previous
//
#include <hip/hip_runtime.h>
#include <math.h>

#define D_MODEL 1024
#define D_INNER 2048
#define DPROJ   96      // DT_RANK + 2*D_STATE
#define DT_RANK 64
#define NSTATE  16
#define SEQ     2048
#define CL      16      // chunk length for scan
#define NCH     (SEQ/CL)            // 128
#define SCAN_SEGS 4
#define SCAN_CPS  (NCH / SCAN_SEGS) // 32 chunks per segment-lane
#define LOG2E   1.44269504088896340736f
#define TDC     ((size_t)SEQ * D_MODEL)   // compile-time TD stride for partials

typedef unsigned short ushort_t;
typedef short v8s __attribute__((ext_vector_type(8)));
typedef unsigned short u8s __attribute__((ext_vector_type(8)));
typedef float v4f __attribute__((ext_vector_type(4)));
typedef __attribute__((address_space(3))) unsigned int as3_u32;
typedef __attribute__((address_space(1))) unsigned int as1_u32;

__device__ __forceinline__ float silu_f(float x) { return x / (1.f + expf(-x)); }

__device__ __forceinline__ ushort_t f2bf(float f) {
  union { float f; unsigned u; } x; x.f = f;
  unsigned r = x.u + 0x7fffu + ((x.u >> 16) & 1u);  // RNE; inputs finite
  return (ushort_t)(r >> 16);
}
__device__ __forceinline__ float bf2f(ushort_t b) {
  union { unsigned u; float f; } x; x.u = ((unsigned)b) << 16; return x.f;
}

// async global->LDS, 16B per lane; lds dest = wave-uniform base + lane*16
__device__ __forceinline__ void gl_lds16(const ushort_t* g, ushort_t* l) {
  __builtin_amdgcn_global_load_lds((const as1_u32*)g, (as3_u32*)l, 16, 0, 0);
}

// x = (pN ? sum of nparts bf16 partials : a) (+ b); res_out = x;
// xn = rmsnorm(x)*w -> f32 (xnf) and/or bf16 (xnb)
__global__ __launch_bounds__(256) void addrms_kernel(
    const float* __restrict__ a, const ushort_t* __restrict__ pN, int nparts,
    const float* __restrict__ b,
    const float* __restrict__ w, float* __restrict__ res_out,
    float* __restrict__ xnf, ushort_t* __restrict__ xnb) {
  int t = blockIdx.x;
  int tid = threadIdx.x;
  float v[4];
  float ss = 0.f;
#pragma unroll
  for (int j = 0; j < 4; ++j) {
    int dcol = tid + j * 256;
    size_t off = (size_t)t * D_MODEL + dcol;
    float x;
    if (pN) {
      x = 0.f;
      for (int p = 0; p < nparts; ++p) x += bf2f(pN[off + (size_t)p * TDC]);
    } else {
      x = a[off];
    }
    if (b) x += b[off];
    v[j] = x;
    ss += x * x;
  }
#pragma unroll
  for (int off = 32; off > 0; off >>= 1) ss += __shfl_down(ss, off);
  __shared__ float red[4];
  __shared__ float rmsv;
  int wid = tid >> 6, lane = tid & 63;
  if (lane == 0) red[wid] = ss;
  __syncthreads();
  if (tid == 0) {
    float s = red[0] + red[1] + red[2] + red[3];
    rmsv = rsqrtf(s / (float)D_MODEL + 1e-5f);
  }
  __syncthreads();
  float r = rmsv;
#pragma unroll
  for (int j = 0; j < 4; ++j) {
    int dcol = tid + j * 256;
    if (res_out) res_out[(size_t)t * D_MODEL + dcol] = v[j];
    float xn = v[j] * r * w[dcol];
    if (xnf) xnf[(size_t)t * D_MODEL + dcol] = xn;
    if (xnb) xnb[(size_t)t * D_MODEL + dcol] = f2bf(xn);
  }
}

// single-dispatch f32->bf16 of all 4 weight tensors (both layers each)
__global__ __launch_bounds__(256) void f2bf_all_kernel(
    const float* __restrict__ s0, ushort_t* __restrict__ d0, int n0,
    const float* __restrict__ s1, ushort_t* __restrict__ d1, int n1,
    const float* __restrict__ s2, ushort_t* __restrict__ d2, int n2,
    const float* __restrict__ s3, ushort_t* __restrict__ d3, int n3) {
  int j = blockIdx.x * 256 + threadIdx.x;
  const float* s; ushort_t* d;
  if (j < n0) { s = s0; d = d0; }
  else {
    j -= n0;
    if (j < n1) { s = s1; d = d1; }
    else {
      j -= n1;
      if (j < n2) { s = s2; d = d2; }
      else {
        j -= n2;
        if (j >= n3) return;
        s = s3; d = d3;
      }
    }
  }
  float4 v = ((const float4*)s)[j];
  ushort4 o;
  o.x = f2bf(v.x); o.y = f2bf(v.y); o.z = f2bf(v.z); o.w = f2bf(v.w);
  ((ushort4*)d)[j] = o;
}

// ------------- bf16 MFMA GEMM (NT): C[m,n] = sum_k A[m,k]*B[n,k] -------------
// m97 structure + double-buffered prefetch; one __syncthreads per K-step.
// XCD-aware bijective block swizzle (m204). SPLITK>1: partials at z*M*ldc.
// NWC = n-frags per wave; tile = 128 x (NWC*32). NWC=2 doubles grid occupancy.
// EPI: 0 = f32 out, 1 = softplus(acc+bias[col]) -> bf16, 2 = bf16.
template <int SPLITK, bool CLAMPN, int EPI, int NWC>
__global__ __launch_bounds__(256) void gemm_bt(
    const ushort_t* __restrict__ A, const ushort_t* __restrict__ B,
    void* __restrict__ Cv, const float* __restrict__ bias,
    int M, int N, int K, int lda, int ldb, int ldc) {
  constexpr int BN = NWC * 32;
  __shared__ ushort_t As[2][128 * 32];
  __shared__ ushort_t Bs[2][BN * 32];
  int tid = threadIdx.x;

  // bijective XCD swizzle of the flattened block id
  int gx = gridDim.x, gy = gridDim.y;
  int nwg = gx * gy * gridDim.z;
  int phys = blockIdx.x + gx * (blockIdx.y + gy * blockIdx.z);
  int q = nwg >> 3, r = nwg & 7;
  int xcd = phys & 7, idx8 = phys >> 3;
  int lbid = (xcd < r ? xcd * (q + 1) : r * (q + 1) + (xcd - r) * q) + idx8;
  int bx = lbid % gx, by = (lbid / gx) % gy, bz = lbid / (gx * gy);

  int bm = by * 128;
  int bn = bx * BN;
  int kchunk = K / SPLITK;
  int k0 = bz * kchunk;
  int nk = kchunk / 32;

  int lane = tid & 63, wid = tid >> 6;
  int wr = wid >> 1, wc = wid & 1;
  int lr = lane & 15;
  int ko = (lane >> 4) * 8;

  int rs0 = wid * 16 + (lane >> 2);
  int segc = (lane & 3) * 8;

  auto stage = [&](int buf, int kt) {
#pragma unroll
    for (int s = 0; s < 2; ++s) {
      int r2 = s * 64 + rs0;
      int cc = kt + segc;
      gl_lds16(A + (size_t)(bm + r2) * lda + cc, &As[buf][s * 2048 + wid * 512]);
    }
#pragma unroll
    for (int s = 0; s < BN / 64; ++s) {
      int r2 = s * 64 + rs0;
      int cc = kt + segc;
      int bc = bn + r2;
      if (CLAMPN) bc = min(bc, N - 1);   // in-bounds; junk cols never stored
      gl_lds16(B + (size_t)bc * ldb + cc, &Bs[buf][s * 2048 + wid * 512]);
    }
  };

  v4f acc[4][NWC] = {};

  stage(0, k0);
  __syncthreads();
  int cur = 0;
  for (int it = 0; it < nk; ++it) {
    if (it + 1 < nk) stage(cur ^ 1, k0 + (it + 1) * 32);
    v8s a[4], b[NWC];
#pragma unroll
    for (int m = 0; m < 4; ++m)
      a[m] = *(const v8s*)&As[cur][(wr * 64 + m * 16 + lr) * 32 + ko];
#pragma unroll
    for (int n = 0; n < NWC; ++n)
      b[n] = *(const v8s*)&Bs[cur][(wc * (NWC * 16) + n * 16 + lr) * 32 + ko];
#pragma unroll
    for (int m = 0; m < 4; ++m)
#pragma unroll
      for (int n = 0; n < NWC; ++n)
        acc[m][n] = __builtin_amdgcn_mfma_f32_16x16x32_bf16(a[m], b[n], acc[m][n], 0, 0, 0);
    __syncthreads();
    cur ^= 1;
  }

  float* Cf = (float*)Cv;
  ushort_t* Cb = (ushort_t*)Cv;
  size_t zoff = (SPLITK > 1) ? (size_t)bz * (size_t)M * (size_t)ldc : 0;

#pragma unroll
  for (int m = 0; m < 4; ++m) {
#pragma unroll
    for (int n = 0; n < NWC; ++n) {
      int gc = bn + wc * (NWC * 16) + n * 16 + lr;
      if (gc >= N) continue;
      int gr0 = bm + wr * 64 + m * 16 + (lane >> 4) * 4;
      float bv = (EPI == 1) ? bias[gc] : 0.f;
#pragma unroll
      for (int j = 0; j < 4; ++j) {
        float val = acc[m][n][j];
        size_t idx = zoff + (size_t)(gr0 + j) * ldc + gc;
        if (EPI == 0) {
          Cf[idx] = val;
        } else if (EPI == 1) {
          float x = val + bv;
          x = fmaxf(x, 0.f) + log1pf(expf(-fabsf(x)));
          Cb[idx] = f2bf(x);
        } else {
          Cb[idx] = f2bf(val);
        }
      }
    }
  }
}

// ---------- fused conv_silu + x_proj K-slice GEMM ----------
// grid (1, 16 M-tiles, 16 K-slices). Block (by,bz):
//  phase 1: conv+silu for t in [bm,bm+128), c in [bz*128,bz*128+128)
//           -> LDS A-tile [128][136] (padded, 16B rows) AND global xcb.
//  phase 2: 128x96 GEMM vs xpwb rows, K-slice of 128, A from resident LDS,
//           B double-buffered via global_load_lds; bf16 partial out.
__global__ __launch_bounds__(256) void convxproj_kernel(
    const ushort_t* __restrict__ xzb, const float* __restrict__ cw,
    const float* __restrict__ cb, const ushort_t* __restrict__ Bw,
    ushort_t* __restrict__ xcb, ushort_t* __restrict__ pkb) {
  __shared__ ushort_t As[128][136];   // 272B rows: 16B-aligned, 2-way banks
  __shared__ ushort_t Bs[2][128 * 32];
  int tid = threadIdx.x;
  int bm = blockIdx.y * 128;
  int c0s = blockIdx.z * 128;         // channel / K-slice offset
  int k0 = c0s;

  // ---- phase 1: conv ----
  {
    int quad = tid & 31;              // 4 channels each
    int tg = tid >> 5;                // 8 groups x 16 t
    int cc = c0s + quad * 4;
    int tbase = bm + tg * 16;
    float4 cbv = *(const float4*)&cb[cc];
    float4 wv[4];
#pragma unroll
    for (int i = 0; i < 4; ++i) wv[i] = *(const float4*)&cw[(cc + i) * 4];
    float rw[4][4];                   // ring of last 4 rows (compile-time idx)
#pragma unroll
    for (int p = 0; p < 3; ++p) {
      int ts = tbase - 3 + p;
      if (ts < 0) {
        rw[p][0] = rw[p][1] = rw[p][2] = rw[p][3] = 0.f;
      } else {
        ushort4 x = *(const ushort4*)&xzb[(size_t)ts * 4096 + cc];
        rw[p][0] = bf2f(x.x); rw[p][1] = bf2f(x.y);
        rw[p][2] = bf2f(x.z); rw[p][3] = bf2f(x.w);
      }
    }
#pragma unroll
    for (int j = 0; j < 16; ++j) {
      int t = tbase + j;
      {
        ushort4 x = *(const ushort4*)&xzb[(size_t)t * 4096 + cc];
        rw[(3 + j) & 3][0] = bf2f(x.x); rw[(3 + j) & 3][1] = bf2f(x.y);
        rw[(3 + j) & 3][2] = bf2f(x.z); rw[(3 + j) & 3][3] = bf2f(x.w);
      }
      float acc[4] = {cbv.x, cbv.y, cbv.z, cbv.w};
#pragma unroll
      for (int k = 0; k < 4; ++k) {
#pragma unroll
        for (int i = 0; i < 4; ++i)
          acc[i] = fmaf(rw[(j + k) & 3][i], ((const float*)&wv[i])[k], acc[i]);
      }
      ushort4 o;
      o.x = f2bf(silu_f(acc[0]));
      o.y = f2bf(silu_f(acc[1]));
      o.z = f2bf(silu_f(acc[2]));
      o.w = f2bf(silu_f(acc[3]));
      *(ushort4*)&As[tg * 16 + j][quad * 4] = o;
      *(ushort4*)&xcb[(size_t)t * D_INNER + cc] = o;
    }
  }

  // ---- phase 2: GEMM (A resident in LDS) ----
  int lane = tid & 63, wid = tid >> 6;
  int wr = wid >> 1, wc = wid & 1;
  int lr = lane & 15;
  int ko = (lane >> 4) * 8;
  int rs0 = wid * 16 + (lane >> 2);
  int segc = (lane & 3) * 8;

  auto stageB = [&](int buf, int it) {
#pragma unroll
    for (int s = 0; s < 2; ++s) {
      int r2 = s * 64 + rs0;
      int bc = min(r2, DPROJ - 1);
      int cc2 = k0 + it * 32 + segc;
      gl_lds16(Bw + (size_t)bc * D_INNER + cc2, &Bs[buf][s * 2048 + wid * 512]);
    }
  };

  v4f acc[4][4] = {};
  stageB(0, 0);
  __syncthreads();     // covers conv As writes + Bs[0]
  int cur = 0;
  for (int it = 0; it < 4; ++it) {
    if (it + 1 < 4) stageB(cur ^ 1, it + 1);
    v8s a[4], b[4];
#pragma unroll
    for (int m = 0; m < 4; ++m)
      a[m] = *(const v8s*)&As[wr * 64 + m * 16 + lr][it * 32 + ko];
#pragma unroll
    for (int n = 0; n < 4; ++n)
      b[n] = *(const v8s*)&Bs[cur][(wc * 64 + n * 16 + lr) * 32 + ko];
#pragma unroll
    for (int m = 0; m < 4; ++m)
#pragma unroll
      for (int n = 0; n < 4; ++n)
        acc[m][n] = __builtin_amdgcn_mfma_f32_16x16x32_bf16(a[m], b[n], acc[m][n], 0, 0, 0);
    __syncthreads();
    cur ^= 1;
  }

  size_t zoff = (size_t)blockIdx.z * (size_t)SEQ * DPROJ;
#pragma unroll
  for (int m = 0; m < 4; ++m) {
#pragma unroll
    for (int n = 0; n < 4; ++n) {
      int gc = wc * 64 + n * 16 + lr;
      if (gc >= DPROJ) continue;
      int gr0 = bm + wr * 64 + m * 16 + (lane >> 4) * 4;
#pragma unroll
      for (int j = 0; j < 4; ++j)
        pkb[zoff + (size_t)(gr0 + j) * DPROJ + gc] = f2bf(acc[m][n][j]);
    }
  }
}

// outb[idx] = bf16( sum_p bf2f(part[idx + p*sz]) )
__global__ __launch_bounds__(256) void reduceNb_kernel(
    const ushort_t* __restrict__ part, ushort_t* __restrict__ outb,
    int sz, int nparts) {
  int idx = blockIdx.x * 256 + threadIdx.x;
  if (idx >= sz) return;
  float s = 0.f;
  for (int p = 0; p < nparts; ++p) s += bf2f(part[idx + (size_t)p * sz]);
  outb[idx] = f2bf(s);
}

// Pass A: per-chunk cumulative dA product + local end state (h0 = 0).
__global__ __launch_bounds__(256) void scan_passA_kernel(
    const ushort_t* __restrict__ dtbb, const ushort_t* __restrict__ xcb,
    const ushort_t* __restrict__ dbcb, const float* __restrict__ A_log,
    ushort_t* __restrict__ aprodb, ushort_t* __restrict__ hendb) {
  __shared__ float Bsh[CL][16];
  int c = blockIdx.x;
  int d = blockIdx.y * 256 + threadIdx.x;
  int t0 = c * CL;
  {
    int j = threadIdx.x;           // CL*16/4 = 64 ushort4 slots
    if (j < CL * 4) {
      int r = j >> 2, col = (j & 3) * 4;
      ushort4 v = *(const ushort4*)&dbcb[(size_t)(t0 + r) * DPROJ + DT_RANK + col];
      Bsh[r][col]     = bf2f(v.x);
      Bsh[r][col + 1] = bf2f(v.y);
      Bsh[r][col + 2] = bf2f(v.z);
      Bsh[r][col + 3] = bf2f(v.w);
    }
  }
  float Av[NSTATE], h[NSTATE], ap[NSTATE];
#pragma unroll
  for (int n = 0; n < NSTATE; ++n) {
    Av[n] = -expf(A_log[(size_t)d * NSTATE + n]) * LOG2E;
    h[n] = 0.f;
    ap[n] = 1.f;
  }
  __syncthreads();
#pragma unroll 2
  for (int tt = 0; tt < CL; ++tt) {
    int t = t0 + tt;
    float dtv = bf2f(dtbb[(size_t)t * D_INNER + d]);
    float uv  = bf2f(xcb[(size_t)t * D_INNER + d]);
    float du = dtv * uv;
#pragma unroll
    for (int n = 0; n < NSTATE; ++n) {
      float dA = exp2f(dtv * Av[n]);
      h[n] = fmaf(dA, h[n], du * Bsh[tt][n]);
      ap[n] *= dA;
    }
  }
  size_t base = ((size_t)c * D_INNER + d) * NSTATE;
  u8s oa, ob, ha, hb;
#pragma unroll
  for (int n = 0; n < 8; ++n) {
    oa[n] = f2bf(ap[n]);     ob[n] = f2bf(ap[n + 8]);
    ha[n] = f2bf(h[n]);      hb[n] = f2bf(h[n + 8]);
  }
  *(u8s*)&aprodb[base] = oa;     *(u8s*)&aprodb[base + 8] = ob;
  *(u8s*)&hendb[base]  = ha;     *(u8s*)&hendb[base + 8]  = hb;
}

// Pass B: carry across 128 chunks (bf16 state in/out).
__global__ __launch_bounds__(256) void scan_passB_kernel(
    const ushort_t* __restrict__ aprodb, ushort_t* __restrict__ hendb) {
  int tid = threadIdx.x;
  int lane = tid & 63;
  int wave = tid >> 6;
  int seg = lane >> 4;                       // 0..3
  int chain = blockIdx.x * 64 + wave * 16 + (lane & 15);
  const size_t stride = (size_t)D_INNER * NSTATE;
  float a[SCAN_CPS], e[SCAN_CPS];
  float P = 1.f, E = 0.f;
  int c0 = seg * SCAN_CPS;
#pragma unroll
  for (int j = 0; j < SCAN_CPS; ++j) {
    a[j] = bf2f(aprodb[(size_t)(c0 + j) * stride + chain]);
    e[j] = bf2f(hendb[(size_t)(c0 + j) * stride + chain]);
    E = fmaf(a[j], E, e[j]);
    P *= a[j];
  }
#pragma unroll
  for (int dstep = 1; dstep < SCAN_SEGS; dstep <<= 1) {
    float Pp = __shfl_up(P, dstep * 16);
    float Ep = __shfl_up(E, dstep * 16);
    if (seg >= dstep) { E = fmaf(P, Ep, E); P *= Pp; }
  }
  float Ex = __shfl_up(E, 16);
  if (seg == 0) Ex = 0.f;
  float h = Ex;
#pragma unroll
  for (int j = 0; j < SCAN_CPS; ++j) {
    hendb[(size_t)(c0 + j) * stride + chain] = f2bf(h);
    h = fmaf(a[j], h, e[j]);
  }
}

// Pass C: rescan from bf16 hin; y = (scan + u*D) * silu(z) -> bf16.
__global__ __launch_bounds__(256) void scan_passC_kernel(
    const ushort_t* __restrict__ dtbb, const ushort_t* __restrict__ xcb,
    const ushort_t* __restrict__ dbcb, const float* __restrict__ A_log,
    const float* __restrict__ Dp, const ushort_t* __restrict__ xzb,
    const ushort_t* __restrict__ hinb, ushort_t* __restrict__ yb) {
  __shared__ float BCsh[CL][32];   // [tt][0..15]=B, [16..31]=C
  int c = blockIdx.x;
  int d = blockIdx.y * 256 + threadIdx.x;
  int t0 = c * CL;
  {
    int j = threadIdx.x;           // CL*32/4 = 128 ushort4 slots
    if (j < CL * 8) {
      int r = j >> 3, col = (j & 7) * 4;
      ushort4 v = *(const ushort4*)&dbcb[(size_t)(t0 + r) * DPROJ + DT_RANK + col];
      BCsh[r][col]     = bf2f(v.x);
      BCsh[r][col + 1] = bf2f(v.y);
      BCsh[r][col + 2] = bf2f(v.z);
      BCsh[r][col + 3] = bf2f(v.w);
    }
  }
  float Av[NSTATE], h[NSTATE];
  size_t base = ((size_t)c * D_INNER + d) * NSTATE;
  u8s h0 = *(const u8s*)&hinb[base];
  u8s h1 = *(const u8s*)&hinb[base + 8];
#pragma unroll
  for (int n = 0; n < NSTATE; ++n) {
    Av[n] = -expf(A_log[(size_t)d * NSTATE + n]) * LOG2E;
    h[n] = (n < 8) ? bf2f(h0[n & 7]) : bf2f(h1[n & 7]);
  }
  float Dv = Dp[d];
  __syncthreads();
#pragma unroll 2
  for (int tt = 0; tt < CL; ++tt) {
    int t = t0 + tt;
    float dtv = bf2f(dtbb[(size_t)t * D_INNER + d]);
    float uv  = bf2f(xcb[(size_t)t * D_INNER + d]);
    float du = dtv * uv;
    float yv = 0.f;
#pragma unroll
    for (int n = 0; n < NSTATE; ++n) {
      float dA = exp2f(dtv * Av[n]);
      h[n] = fmaf(dA, h[n], du * BCsh[tt][n]);
      yv = fmaf(h[n], BCsh[tt][16 + n], yv);
    }
    float zv = bf2f(xzb[(size_t)t * 4096 + D_INNER + d]);
    yb[(size_t)t * D_INNER + d] = f2bf((yv + uv * Dv) * silu_f(zv));
  }
}

extern "C" void kernel_launch(void* const* d_in, const int* in_sizes, int n_in,
                              void* d_out, int out_size, void* d_ws, size_t ws_size,
                              hipStream_t stream) {
  const float* h_in   = (const float*)d_in[0];
  const float* norm_w = (const float*)d_in[1];
  const float* in_w   = (const float*)d_in[2];
  const float* conv_w = (const float*)d_in[3];
  const float* conv_b = (const float*)d_in[4];
  const float* xp_w   = (const float*)d_in[5];
  const float* dt_w   = (const float*)d_in[6];
  const float* dt_b   = (const float*)d_in[7];
  const float* A_log  = (const float*)d_in[8];
  const float* Dp     = (const float*)d_in[9];
  const float* out_w  = (const float*)d_in[10];
  const float* normf  = (const float*)d_in[11];
  float* out = (float*)d_out;

  float* ws = (float*)d_ws;
  const size_t TD = (size_t)SEQ * D_MODEL;            // 2.10M
  const size_t TI = (size_t)SEQ * D_INNER;            // 4.19M
  const size_t ST = (size_t)NCH * D_INNER * NSTATE;   // 4.19M elements
  const size_t DB = (size_t)SEQ * DPROJ;
  const size_t INW = (size_t)2 * D_INNER * D_MODEL;
  const size_t XPW = (size_t)DPROJ * D_INNER;
  const size_t DTW = (size_t)D_INNER * DT_RANK;
  const size_t OUW = (size_t)D_MODEL * D_INNER;

  float* res = ws; ws += TD;
  ushort_t* us = (ushort_t*)ws;
  ushort_t* pkb    = us;  us += 4 * TD;   // out_proj 4 partials / x_proj 16 partials
  ushort_t* aprodb = us;  us += ST;
  ushort_t* hendb  = us;  us += ST;       // hin after passB
  ushort_t* hnb    = us;  us += TD;
  ushort_t* xzb    = us;  us += 2 * TI;
  ushort_t* xcb    = us;  us += TI;
  ushort_t* dtbb   = us;  us += TI;
  ushort_t* ybf    = us;  us += TI;
  ushort_t* dbcb   = us;  us += DB;
  ushort_t* inwb   = us;  us += 2 * INW;
  ushort_t* xpwb   = us;  us += 2 * XPW;
  ushort_t* dtwb   = us;  us += 2 * DTW;
  ushort_t* ouwb   = us;  us += 2 * OUW;

  // convert ALL weights (both layers) in one dispatch
  {
    int n0 = (int)(2 * INW / 4), n1 = (int)(2 * XPW / 4);
    int n2 = (int)(2 * DTW / 4), n3 = (int)(2 * OUW / 4);
    int tot = n0 + n1 + n2 + n3;
    f2bf_all_kernel<<<(tot + 255) / 256, 256, 0, stream>>>(
        in_w, inwb, n0, xp_w, xpwb, n1, dt_w, dtwb, n2, out_w, ouwb, n3);
  }

  for (int i = 0; i < 2; ++i) {
    // residual update + rmsnorm; layer>0 consumes bf16 out_proj split-K=4 partials
    addrms_kernel<<<SEQ, 256, 0, stream>>>(
        h_in, i == 0 ? nullptr : pkb, 4,
        i == 0 ? nullptr : res,
        norm_w + (size_t)i * D_MODEL, res, nullptr, hnb);
    // in_proj: [2048 x 1024] x [4096 x 1024]^T -> xzb (bf16); BN=64, 1024 blocks
    gemm_bt<1, false, 2, 2><<<dim3(64, 16, 1), 256, 0, stream>>>(
        hnb, inwb + (size_t)i * INW, xzb, nullptr,
        SEQ, 2 * D_INNER, D_MODEL, D_MODEL, D_MODEL, 2 * D_INNER);
    // fused conv+silu (-> xcb) + x_proj K-slice GEMM (-> pkb bf16 partials x16)
    convxproj_kernel<<<dim3(1, 16, 16), 256, 0, stream>>>(
        xzb, conv_w + (size_t)i * D_INNER * 4, conv_b + (size_t)i * D_INNER,
        xpwb + (size_t)i * XPW, xcb, pkb);
    reduceNb_kernel<<<(DB + 255) / 256, 256, 0, stream>>>(pkb, dbcb, (int)DB, 16);
    // dt_proj -> softplus -> dtbb (bf16); BN=64, 512 blocks
    gemm_bt<1, false, 1, 2><<<dim3(32, 16, 1), 256, 0, stream>>>(
        dbcb, dtwb + (size_t)i * DTW, dtbb, dt_b + (size_t)i * D_INNER,
        SEQ, D_INNER, DT_RANK, DPROJ, DT_RANK, D_INNER);
    // scan: A -> B -> C (3 dispatches, bf16 state)
    scan_passA_kernel<<<dim3(NCH, D_INNER / 256), 256, 0, stream>>>(
        dtbb, xcb, dbcb, A_log + (size_t)i * D_INNER * NSTATE, aprodb, hendb);
    scan_passB_kernel<<<(D_INNER * NSTATE) / 64, 256, 0, stream>>>(aprodb, hendb);
    scan_passC_kernel<<<dim3(NCH, D_INNER / 256), 256, 0, stream>>>(
        dtbb, xcb, dbcb, A_log + (size_t)i * D_INNER * NSTATE,
        Dp + (size_t)i * D_INNER, xzb, hendb, ybf);
    // out_proj: split-K=4 -> pkb (bf16 partials, 4 x TD); BN=64, 1024 blocks
    gemm_bt<4, false, 2, 2><<<dim3(16, 16, 4), 256, 0, stream>>>(
        ybf, ouwb + (size_t)i * OUW, pkb, nullptr,
        SEQ, D_MODEL, D_INNER, D_INNER, D_INNER, D_MODEL);
  }
  addrms_kernel<<<SEQ, 256, 0, stream>>>(
      h_in, pkb, 4, res, normf, nullptr, out, nullptr);
}

// Round 18
// 323.350 us; speedup vs baseline: 1.1397x; 1.0067x over previous
//
#include <hip/hip_runtime.h>
#include <math.h>

#define D_MODEL 1024
#define D_INNER 2048
#define DPROJ   96      // DT_RANK + 2*D_STATE
#define DT_RANK 64
#define NSTATE  16
#define SEQ     2048
#define CL      16      // chunk length for scan
#define NCH     (SEQ/CL)            // 128
#define SCAN_SEGS 4
#define SCAN_CPS  (NCH / SCAN_SEGS) // 32 chunks per segment-lane
#define LOG2E   1.44269504088896340736f
#define TDC     ((size_t)SEQ * D_MODEL)   // compile-time TD stride for partials

typedef unsigned short ushort_t;
typedef short v8s __attribute__((ext_vector_type(8)));
typedef unsigned short u8s __attribute__((ext_vector_type(8)));
typedef float v4f __attribute__((ext_vector_type(4)));
typedef __attribute__((address_space(3))) unsigned int as3_u32;
typedef __attribute__((address_space(1))) unsigned int as1_u32;

__device__ __forceinline__ float silu_f(float x) { return x / (1.f + expf(-x)); }

__device__ __forceinline__ ushort_t f2bf(float f) {
  union { float f; unsigned u; } x; x.f = f;
  unsigned r = x.u + 0x7fffu + ((x.u >> 16) & 1u);  // RNE; inputs finite
  return (ushort_t)(r >> 16);
}
__device__ __forceinline__ float bf2f(ushort_t b) {
  union { unsigned u; float f; } x; x.u = ((unsigned)b) << 16; return x.f;
}

// async global->LDS, 16B per lane; lds dest = wave-uniform base + lane*16
__device__ __forceinline__ void gl_lds16(const ushort_t* g, ushort_t* l) {
  __builtin_amdgcn_global_load_lds((const as1_u32*)g, (as3_u32*)l, 16, 0, 0);
}

// x = (pN ? sum of nparts bf16 partials : a) (+ b); res_out = x;
// xn = rmsnorm(x)*w -> f32 (xnf) and/or bf16 (xnb)
__global__ __launch_bounds__(256) void addrms_kernel(
    const float* __restrict__ a, const ushort_t* __restrict__ pN, int nparts,
    const float* __restrict__ b,
    const float* __restrict__ w, float* __restrict__ res_out,
    float* __restrict__ xnf, ushort_t* __restrict__ xnb) {
  int t = blockIdx.x;
  int tid = threadIdx.x;
  float v[4];
  float ss = 0.f;
#pragma unroll
  for (int j = 0; j < 4; ++j) {
    int dcol = tid + j * 256;
    size_t off = (size_t)t * D_MODEL + dcol;
    float x;
    if (pN) {
      x = 0.f;
      for (int p = 0; p < nparts; ++p) x += bf2f(pN[off + (size_t)p * TDC]);
    } else {
      x = a[off];
    }
    if (b) x += b[off];
    v[j] = x;
    ss += x * x;
  }
#pragma unroll
  for (int off = 32; off > 0; off >>= 1) ss += __shfl_down(ss, off);
  __shared__ float red[4];
  __shared__ float rmsv;
  int wid = tid >> 6, lane = tid & 63;
  if (lane == 0) red[wid] = ss;
  __syncthreads();
  if (tid == 0) {
    float s = red[0] + red[1] + red[2] + red[3];
    rmsv = rsqrtf(s / (float)D_MODEL + 1e-5f);
  }
  __syncthreads();
  float r = rmsv;
#pragma unroll
  for (int j = 0; j < 4; ++j) {
    int dcol = tid + j * 256;
    if (res_out) res_out[(size_t)t * D_MODEL + dcol] = v[j];
    float xn = v[j] * r * w[dcol];
    if (xnf) xnf[(size_t)t * D_MODEL + dcol] = xn;
    if (xnb) xnb[(size_t)t * D_MODEL + dcol] = f2bf(xn);
  }
}

// single-dispatch f32->bf16 of all 4 weight tensors (both layers each)
__global__ __launch_bounds__(256) void f2bf_all_kernel(
    const float* __restrict__ s0, ushort_t* __restrict__ d0, int n0,
    const float* __restrict__ s1, ushort_t* __restrict__ d1, int n1,
    const float* __restrict__ s2, ushort_t* __restrict__ d2, int n2,
    const float* __restrict__ s3, ushort_t* __restrict__ d3, int n3) {
  int j = blockIdx.x * 256 + threadIdx.x;
  const float* s; ushort_t* d;
  if (j < n0) { s = s0; d = d0; }
  else {
    j -= n0;
    if (j < n1) { s = s1; d = d1; }
    else {
      j -= n1;
      if (j < n2) { s = s2; d = d2; }
      else {
        j -= n2;
        if (j >= n3) return;
        s = s3; d = d3;
      }
    }
  }
  float4 v = ((const float4*)s)[j];
  ushort4 o;
  o.x = f2bf(v.x); o.y = f2bf(v.y); o.z = f2bf(v.z); o.w = f2bf(v.w);
  ((ushort4*)d)[j] = o;
}

// ------------- bf16 MFMA GEMM (NT): C[m,n] = sum_k A[m,k]*B[n,k] -------------
// m97 structure + double-buffered prefetch; one __syncthreads per K-step.
// XCD-aware bijective block swizzle (m204). SPLITK>1: partials at z*M*ldc.
// NWC = n-frags per wave; tile = 128 x (NWC*32).
// EPI: 0 = f32 out, 1 = softplus(acc+bias[col]) -> bf16, 2 = bf16.
template <int SPLITK, bool CLAMPN, int EPI, int NWC>
__global__ __launch_bounds__(256) void gemm_bt(
    const ushort_t* __restrict__ A, const ushort_t* __restrict__ B,
    void* __restrict__ Cv, const float* __restrict__ bias,
    int M, int N, int K, int lda, int ldb, int ldc) {
  constexpr int BN = NWC * 32;
  __shared__ ushort_t As[2][128 * 32];
  __shared__ ushort_t Bs[2][BN * 32];
  int tid = threadIdx.x;

  // bijective XCD swizzle of the flattened block id
  int gx = gridDim.x, gy = gridDim.y;
  int nwg = gx * gy * gridDim.z;
  int phys = blockIdx.x + gx * (blockIdx.y + gy * blockIdx.z);
  int q = nwg >> 3, r = nwg & 7;
  int xcd = phys & 7, idx8 = phys >> 3;
  int lbid = (xcd < r ? xcd * (q + 1) : r * (q + 1) + (xcd - r) * q) + idx8;
  int bx = lbid % gx, by = (lbid / gx) % gy, bz = lbid / (gx * gy);

  int bm = by * 128;
  int bn = bx * BN;
  int kchunk = K / SPLITK;
  int k0 = bz * kchunk;
  int nk = kchunk / 32;

  int lane = tid & 63, wid = tid >> 6;
  int wr = wid >> 1, wc = wid & 1;
  int lr = lane & 15;
  int ko = (lane >> 4) * 8;

  int rs0 = wid * 16 + (lane >> 2);
  int segc = (lane & 3) * 8;

  auto stage = [&](int buf, int kt) {
#pragma unroll
    for (int s = 0; s < 2; ++s) {
      int r2 = s * 64 + rs0;
      int cc = kt + segc;
      gl_lds16(A + (size_t)(bm + r2) * lda + cc, &As[buf][s * 2048 + wid * 512]);
    }
#pragma unroll
    for (int s = 0; s < BN / 64; ++s) {
      int r2 = s * 64 + rs0;
      int cc = kt + segc;
      int bc = bn + r2;
      if (CLAMPN) bc = min(bc, N - 1);   // in-bounds; junk cols never stored
      gl_lds16(B + (size_t)bc * ldb + cc, &Bs[buf][s * 2048 + wid * 512]);
    }
  };

  v4f acc[4][NWC] = {};

  stage(0, k0);
  __syncthreads();
  int cur = 0;
  for (int it = 0; it < nk; ++it) {
    if (it + 1 < nk) stage(cur ^ 1, k0 + (it + 1) * 32);
    v8s a[4], b[NWC];
#pragma unroll
    for (int m = 0; m < 4; ++m)
      a[m] = *(const v8s*)&As[cur][(wr * 64 + m * 16 + lr) * 32 + ko];
#pragma unroll
    for (int n = 0; n < NWC; ++n)
      b[n] = *(const v8s*)&Bs[cur][(wc * (NWC * 16) + n * 16 + lr) * 32 + ko];
#pragma unroll
    for (int m = 0; m < 4; ++m)
#pragma unroll
      for (int n = 0; n < NWC; ++n)
        acc[m][n] = __builtin_amdgcn_mfma_f32_16x16x32_bf16(a[m], b[n], acc[m][n], 0, 0, 0);
    __syncthreads();
    cur ^= 1;
  }

  float* Cf = (float*)Cv;
  ushort_t* Cb = (ushort_t*)Cv;
  size_t zoff = (SPLITK > 1) ? (size_t)bz * (size_t)M * (size_t)ldc : 0;

#pragma unroll
  for (int m = 0; m < 4; ++m) {
#pragma unroll
    for (int n = 0; n < NWC; ++n) {
      int gc = bn + wc * (NWC * 16) + n * 16 + lr;
      if (gc >= N) continue;
      int gr0 = bm + wr * 64 + m * 16 + (lane >> 4) * 4;
      float bv = (EPI == 1) ? bias[gc] : 0.f;
#pragma unroll
      for (int j = 0; j < 4; ++j) {
        float val = acc[m][n][j];
        size_t idx = zoff + (size_t)(gr0 + j) * ldc + gc;
        if (EPI == 0) {
          Cf[idx] = val;
        } else if (EPI == 1) {
          float x = val + bv;
          x = fmaxf(x, 0.f) + log1pf(expf(-fabsf(x)));
          Cb[idx] = f2bf(x);
        } else {
          Cb[idx] = f2bf(val);
        }
      }
    }
  }
}

// ---------- fused conv_silu + x_proj K-slice GEMM (64-row M-tiles) ----------
// grid (1, 32 M-tiles, 16 K-slices). Block (by,bz):
//  phase 1: conv+silu for t in [bm,bm+64), c in [bz*128,bz*128+128)
//           -> LDS A-tile [64][136] AND global xcb.
//  phase 2: 64x96 GEMM vs xpwb rows, K-slice of 128, A resident in LDS,
//           B double-buffered via global_load_lds; bf16 partial out.
__global__ __launch_bounds__(256) void convxproj_kernel(
    const ushort_t* __restrict__ xzb, const float* __restrict__ cw,
    const float* __restrict__ cb, const ushort_t* __restrict__ Bw,
    ushort_t* __restrict__ xcb, ushort_t* __restrict__ pkb) {
  __shared__ ushort_t As[64][136];    // 272B rows: 16B-aligned, 2-way banks
  __shared__ ushort_t Bs[2][128 * 32];
  int tid = threadIdx.x;
  int bm = blockIdx.y * 64;
  int c0s = blockIdx.z * 128;         // channel / K-slice offset
  int k0 = c0s;

  // ---- phase 1: conv (8 t-steps x 4 channels per thread) ----
  {
    int quad = tid & 31;              // 4 channels each
    int tg = tid >> 5;                // 8 groups x 8 t
    int cc = c0s + quad * 4;
    int tbase = bm + tg * 8;
    float4 cbv = *(const float4*)&cb[cc];
    float4 wv[4];
#pragma unroll
    for (int i = 0; i < 4; ++i) wv[i] = *(const float4*)&cw[(cc + i) * 4];
    float rw[4][4];                   // ring of last 4 rows (compile-time idx)
#pragma unroll
    for (int p = 0; p < 3; ++p) {
      int ts = tbase - 3 + p;
      if (ts < 0) {
        rw[p][0] = rw[p][1] = rw[p][2] = rw[p][3] = 0.f;
      } else {
        ushort4 x = *(const ushort4*)&xzb[(size_t)ts * 4096 + cc];
        rw[p][0] = bf2f(x.x); rw[p][1] = bf2f(x.y);
        rw[p][2] = bf2f(x.z); rw[p][3] = bf2f(x.w);
      }
    }
#pragma unroll
    for (int j = 0; j < 8; ++j) {
      int t = tbase + j;
      {
        ushort4 x = *(const ushort4*)&xzb[(size_t)t * 4096 + cc];
        rw[(3 + j) & 3][0] = bf2f(x.x); rw[(3 + j) & 3][1] = bf2f(x.y);
        rw[(3 + j) & 3][2] = bf2f(x.z); rw[(3 + j) & 3][3] = bf2f(x.w);
      }
      float acc[4] = {cbv.x, cbv.y, cbv.z, cbv.w};
#pragma unroll
      for (int k = 0; k < 4; ++k) {
#pragma unroll
        for (int i = 0; i < 4; ++i)
          acc[i] = fmaf(rw[(j + k) & 3][i], ((const float*)&wv[i])[k], acc[i]);
      }
      ushort4 o;
      o.x = f2bf(silu_f(acc[0]));
      o.y = f2bf(silu_f(acc[1]));
      o.z = f2bf(silu_f(acc[2]));
      o.w = f2bf(silu_f(acc[3]));
      *(ushort4*)&As[tg * 8 + j][quad * 4] = o;
      *(ushort4*)&xcb[(size_t)t * D_INNER + cc] = o;
    }
  }

  // ---- phase 2: GEMM 64x96 (A resident in LDS) ----
  int lane = tid & 63, wid = tid >> 6;
  int wr = wid >> 1, wc = wid & 1;
  int lr = lane & 15;
  int ko = (lane >> 4) * 8;
  int rs0 = wid * 16 + (lane >> 2);
  int segc = (lane & 3) * 8;

  auto stageB = [&](int buf, int it) {
#pragma unroll
    for (int s = 0; s < 2; ++s) {
      int r2 = s * 64 + rs0;
      int bc = min(r2, DPROJ - 1);
      int cc2 = k0 + it * 32 + segc;
      gl_lds16(Bw + (size_t)bc * D_INNER + cc2, &Bs[buf][s * 2048 + wid * 512]);
    }
  };

  v4f acc[2][4] = {};
  stageB(0, 0);
  __syncthreads();     // covers conv As writes + Bs[0]
  int cur = 0;
  for (int it = 0; it < 4; ++it) {
    if (it + 1 < 4) stageB(cur ^ 1, it + 1);
    v8s a[2], b[4];
#pragma unroll
    for (int m = 0; m < 2; ++m)
      a[m] = *(const v8s*)&As[wr * 32 + m * 16 + lr][it * 32 + ko];
#pragma unroll
    for (int n = 0; n < 4; ++n)
      b[n] = *(const v8s*)&Bs[cur][(wc * 64 + n * 16 + lr) * 32 + ko];
#pragma unroll
    for (int m = 0; m < 2; ++m)
#pragma unroll
      for (int n = 0; n < 4; ++n)
        acc[m][n] = __builtin_amdgcn_mfma_f32_16x16x32_bf16(a[m], b[n], acc[m][n], 0, 0, 0);
    __syncthreads();
    cur ^= 1;
  }

  size_t zoff = (size_t)blockIdx.z * (size_t)SEQ * DPROJ;
#pragma unroll
  for (int m = 0; m < 2; ++m) {
#pragma unroll
    for (int n = 0; n < 4; ++n) {
      int gc = wc * 64 + n * 16 + lr;
      if (gc >= DPROJ) continue;
      int gr0 = bm + wr * 32 + m * 16 + (lane >> 4) * 4;
#pragma unroll
      for (int j = 0; j < 4; ++j)
        pkb[zoff + (size_t)(gr0 + j) * DPROJ + gc] = f2bf(acc[m][n][j]);
    }
  }
}

// outb[idx] = bf16( sum_p bf2f(part[idx + p*sz]) )
__global__ __launch_bounds__(256) void reduceNb_kernel(
    const ushort_t* __restrict__ part, ushort_t* __restrict__ outb,
    int sz, int nparts) {
  int idx = blockIdx.x * 256 + threadIdx.x;
  if (idx >= sz) return;
  float s = 0.f;
  for (int p = 0; p < nparts; ++p) s += bf2f(part[idx + (size_t)p * sz]);
  outb[idx] = f2bf(s);
}

// Pass A: per-chunk cumulative dA product + local end state (h0 = 0).
__global__ __launch_bounds__(256) void scan_passA_kernel(
    const ushort_t* __restrict__ dtbb, const ushort_t* __restrict__ xcb,
    const ushort_t* __restrict__ dbcb, const float* __restrict__ A_log,
    ushort_t* __restrict__ aprodb, ushort_t* __restrict__ hendb) {
  __shared__ float Bsh[CL][16];
  int c = blockIdx.x;
  int d = blockIdx.y * 256 + threadIdx.x;
  int t0 = c * CL;
  {
    int j = threadIdx.x;           // CL*16/4 = 64 ushort4 slots
    if (j < CL * 4) {
      int r = j >> 2, col = (j & 3) * 4;
      ushort4 v = *(const ushort4*)&dbcb[(size_t)(t0 + r) * DPROJ + DT_RANK + col];
      Bsh[r][col]     = bf2f(v.x);
      Bsh[r][col + 1] = bf2f(v.y);
      Bsh[r][col + 2] = bf2f(v.z);
      Bsh[r][col + 3] = bf2f(v.w);
    }
  }
  float Av[NSTATE], h[NSTATE], ap[NSTATE];
#pragma unroll
  for (int n = 0; n < NSTATE; ++n) {
    Av[n] = -expf(A_log[(size_t)d * NSTATE + n]) * LOG2E;
    h[n] = 0.f;
    ap[n] = 1.f;
  }
  __syncthreads();
#pragma unroll 2
  for (int tt = 0; tt < CL; ++tt) {
    int t = t0 + tt;
    float dtv = bf2f(dtbb[(size_t)t * D_INNER + d]);
    float uv  = bf2f(xcb[(size_t)t * D_INNER + d]);
    float du = dtv * uv;
#pragma unroll
    for (int n = 0; n < NSTATE; ++n) {
      float dA = exp2f(dtv * Av[n]);
      h[n] = fmaf(dA, h[n], du * Bsh[tt][n]);
      ap[n] *= dA;
    }
  }
  size_t base = ((size_t)c * D_INNER + d) * NSTATE;
  u8s oa, ob, ha, hb;
#pragma unroll
  for (int n = 0; n < 8; ++n) {
    oa[n] = f2bf(ap[n]);     ob[n] = f2bf(ap[n + 8]);
    ha[n] = f2bf(h[n]);      hb[n] = f2bf(h[n + 8]);
  }
  *(u8s*)&aprodb[base] = oa;     *(u8s*)&aprodb[base + 8] = ob;
  *(u8s*)&hendb[base]  = ha;     *(u8s*)&hendb[base + 8]  = hb;
}

// Pass B: carry across 128 chunks (bf16 state in/out).
__global__ __launch_bounds__(256) void scan_passB_kernel(
    const ushort_t* __restrict__ aprodb, ushort_t* __restrict__ hendb) {
  int tid = threadIdx.x;
  int lane = tid & 63;
  int wave = tid >> 6;
  int seg = lane >> 4;                       // 0..3
  int chain = blockIdx.x * 64 + wave * 16 + (lane & 15);
  const size_t stride = (size_t)D_INNER * NSTATE;
  float a[SCAN_CPS], e[SCAN_CPS];
  float P = 1.f, E = 0.f;
  int c0 = seg * SCAN_CPS;
#pragma unroll
  for (int j = 0; j < SCAN_CPS; ++j) {
    a[j] = bf2f(aprodb[(size_t)(c0 + j) * stride + chain]);
    e[j] = bf2f(hendb[(size_t)(c0 + j) * stride + chain]);
    E = fmaf(a[j], E, e[j]);
    P *= a[j];
  }
#pragma unroll
  for (int dstep = 1; dstep < SCAN_SEGS; dstep <<= 1) {
    float Pp = __shfl_up(P, dstep * 16);
    float Ep = __shfl_up(E, dstep * 16);
    if (seg >= dstep) { E = fmaf(P, Ep, E); P *= Pp; }
  }
  float Ex = __shfl_up(E, 16);
  if (seg == 0) Ex = 0.f;
  float h = Ex;
#pragma unroll
  for (int j = 0; j < SCAN_CPS; ++j) {
    hendb[(size_t)(c0 + j) * stride + chain] = f2bf(h);
    h = fmaf(a[j], h, e[j]);
  }
}

// Pass C: rescan from bf16 hin; y = (scan + u*D) * silu(z) -> bf16.
__global__ __launch_bounds__(256) void scan_passC_kernel(
    const ushort_t* __restrict__ dtbb, const ushort_t* __restrict__ xcb,
    const ushort_t* __restrict__ dbcb, const float* __restrict__ A_log,
    const float* __restrict__ Dp, const ushort_t* __restrict__ xzb,
    const ushort_t* __restrict__ hinb, ushort_t* __restrict__ yb) {
  __shared__ float BCsh[CL][32];   // [tt][0..15]=B, [16..31]=C
  int c = blockIdx.x;
  int d = blockIdx.y * 256 + threadIdx.x;
  int t0 = c * CL;
  {
    int j = threadIdx.x;           // CL*32/4 = 128 ushort4 slots
    if (j < CL * 8) {
      int r = j >> 3, col = (j & 7) * 4;
      ushort4 v = *(const ushort4*)&dbcb[(size_t)(t0 + r) * DPROJ + DT_RANK + col];
      BCsh[r][col]     = bf2f(v.x);
      BCsh[r][col + 1] = bf2f(v.y);
      BCsh[r][col + 2] = bf2f(v.z);
      BCsh[r][col + 3] = bf2f(v.w);
    }
  }
  float Av[NSTATE], h[NSTATE];
  size_t base = ((size_t)c * D_INNER + d) * NSTATE;
  u8s h0 = *(const u8s*)&hinb[base];
  u8s h1 = *(const u8s*)&hinb[base + 8];
#pragma unroll
  for (int n = 0; n < NSTATE; ++n) {
    Av[n] = -expf(A_log[(size_t)d * NSTATE + n]) * LOG2E;
    h[n] = (n < 8) ? bf2f(h0[n & 7]) : bf2f(h1[n & 7]);
  }
  float Dv = Dp[d];
  __syncthreads();
#pragma unroll 2
  for (int tt = 0; tt < CL; ++tt) {
    int t = t0 + tt;
    float dtv = bf2f(dtbb[(size_t)t * D_INNER + d]);
    float uv  = bf2f(xcb[(size_t)t * D_INNER + d]);
    float du = dtv * uv;
    float yv = 0.f;
#pragma unroll
    for (int n = 0; n < NSTATE; ++n) {
      float dA = exp2f(dtv * Av[n]);
      h[n] = fmaf(dA, h[n], du * BCsh[tt][n]);
      yv = fmaf(h[n], BCsh[tt][16 + n], yv);
    }
    float zv = bf2f(xzb[(size_t)t * 4096 + D_INNER + d]);
    yb[(size_t)t * D_INNER + d] = f2bf((yv + uv * Dv) * silu_f(zv));
  }
}

extern "C" void kernel_launch(void* const* d_in, const int* in_sizes, int n_in,
                              void* d_out, int out_size, void* d_ws, size_t ws_size,
                              hipStream_t stream) {
  const float* h_in   = (const float*)d_in[0];
  const float* norm_w = (const float*)d_in[1];
  const float* in_w   = (const float*)d_in[2];
  const float* conv_w = (const float*)d_in[3];
  const float* conv_b = (const float*)d_in[4];
  const float* xp_w   = (const float*)d_in[5];
  const float* dt_w   = (const float*)d_in[6];
  const float* dt_b   = (const float*)d_in[7];
  const float* A_log  = (const float*)d_in[8];
  const float* Dp     = (const float*)d_in[9];
  const float* out_w  = (const float*)d_in[10];
  const float* normf  = (const float*)d_in[11];
  float* out = (float*)d_out;

  float* ws = (float*)d_ws;
  const size_t TD = (size_t)SEQ * D_MODEL;            // 2.10M
  const size_t TI = (size_t)SEQ * D_INNER;            // 4.19M
  const size_t ST = (size_t)NCH * D_INNER * NSTATE;   // 4.19M elements
  const size_t DB = (size_t)SEQ * DPROJ;
  const size_t INW = (size_t)2 * D_INNER * D_MODEL;
  const size_t XPW = (size_t)DPROJ * D_INNER;
  const size_t DTW = (size_t)D_INNER * DT_RANK;
  const size_t OUW = (size_t)D_MODEL * D_INNER;

  float* res = ws; ws += TD;
  ushort_t* us = (ushort_t*)ws;
  ushort_t* pkb    = us;  us += 4 * TD;   // out_proj 4 partials / x_proj 16 partials
  ushort_t* aprodb = us;  us += ST;
  ushort_t* hendb  = us;  us += ST;       // hin after passB
  ushort_t* hnb    = us;  us += TD;
  ushort_t* xzb    = us;  us += 2 * TI;
  ushort_t* xcb    = us;  us += TI;
  ushort_t* dtbb   = us;  us += TI;
  ushort_t* ybf    = us;  us += TI;
  ushort_t* dbcb   = us;  us += DB;
  ushort_t* inwb   = us;  us += 2 * INW;
  ushort_t* xpwb   = us;  us += 2 * XPW;
  ushort_t* dtwb   = us;  us += 2 * DTW;
  ushort_t* ouwb   = us;  us += 2 * OUW;

  // convert ALL weights (both layers) in one dispatch
  {
    int n0 = (int)(2 * INW / 4), n1 = (int)(2 * XPW / 4);
    int n2 = (int)(2 * DTW / 4), n3 = (int)(2 * OUW / 4);
    int tot = n0 + n1 + n2 + n3;
    f2bf_all_kernel<<<(tot + 255) / 256, 256, 0, stream>>>(
        in_w, inwb, n0, xp_w, xpwb, n1, dt_w, dtwb, n2, out_w, ouwb, n3);
  }

  for (int i = 0; i < 2; ++i) {
    // residual update + rmsnorm; layer>0 consumes bf16 out_proj split-K=4 partials
    addrms_kernel<<<SEQ, 256, 0, stream>>>(
        h_in, i == 0 ? nullptr : pkb, 4,
        i == 0 ? nullptr : res,
        norm_w + (size_t)i * D_MODEL, res, nullptr, hnb);
    // in_proj: [2048 x 1024] x [4096 x 1024]^T -> xzb (bf16); BN=64, 1024 blocks
    gemm_bt<1, false, 2, 2><<<dim3(64, 16, 1), 256, 0, stream>>>(
        hnb, inwb + (size_t)i * INW, xzb, nullptr,
        SEQ, 2 * D_INNER, D_MODEL, D_MODEL, D_MODEL, 2 * D_INNER);
    // fused conv+silu (-> xcb) + x_proj K-slice GEMM (-> pkb bf16 partials x16)
    convxproj_kernel<<<dim3(1, 32, 16), 256, 0, stream>>>(
        xzb, conv_w + (size_t)i * D_INNER * 4, conv_b + (size_t)i * D_INNER,
        xpwb + (size_t)i * XPW, xcb, pkb);
    reduceNb_kernel<<<(DB + 255) / 256, 256, 0, stream>>>(pkb, dbcb, (int)DB, 16);
    // dt_proj -> softplus -> dtbb (bf16); BN=64, 512 blocks
    gemm_bt<1, false, 1, 2><<<dim3(32, 16, 1), 256, 0, stream>>>(
        dbcb, dtwb + (size_t)i * DTW, dtbb, dt_b + (size_t)i * D_INNER,
        SEQ, D_INNER, DT_RANK, DPROJ, DT_RANK, D_INNER);
    // scan: A -> B -> C (3 dispatches, bf16 state)
    scan_passA_kernel<<<dim3(NCH, D_INNER / 256), 256, 0, stream>>>(
        dtbb, xcb, dbcb, A_log + (size_t)i * D_INNER * NSTATE, aprodb, hendb);
    scan_passB_kernel<<<(D_INNER * NSTATE) / 64, 256, 0, stream>>>(aprodb, hendb);
    scan_passC_kernel<<<dim3(NCH, D_INNER / 256), 256, 0, stream>>>(
        dtbb, xcb, dbcb, A_log + (size_t)i * D_INNER * NSTATE,
        Dp + (size_t)i * D_INNER, xzb, hendb, ybf);
    // out_proj: split-K=4 -> pkb (bf16 partials, 4 x TD); BN=64, 1024 blocks
    gemm_bt<4, false, 2, 2><<<dim3(16, 16, 4), 256, 0, stream>>>(
        ybf, ouwb + (size_t)i * OUW, pkb, nullptr,
        SEQ, D_MODEL, D_INNER, D_INNER, D_INNER, D_MODEL);
  }
  addrms_kernel<<<SEQ, 256, 0, stream>>>(
      h_in, pkb, 4, res, normf, nullptr, out, nullptr);
}